// Round 8
// baseline (138.848 us; speedup 1.0000x reference)
//
#include <hip/hip_runtime.h>
#include <float.h>

// HaloAttn: x(4,128,128,128) f32 -> out(4,128,128,128) f32
// BS=8, HS=3, WIN=14, NH=8, DQK=DV=16, SCALE=0.25
//
// k0: conv_w      q_w|kv_w|proj_w (512x128 f32) -> hi/lo bf16 in ws
// k1: gemm_split  q=x@q_w^T -> ws bf16, kv=x@kv_w^T -> ws bf16   (3-term split MFMA)
// k2: halo_attn   1 head/block (grid.z=8), 1 q-tile/wave; MFMA bf16 swapped QK
// k3: gemm_split  d_out = d_out @ proj_w^T + proj_b (in place, split MFMA)
//
// R8 = R7 + VALU diet: unconditional ak load (upper-K lanes multiply qf=0),
// mask folded into sentinel bias rows (koff2=-200 -> bias=-3e4 -> exp2=0),
// native v_exp_f32, cvt_pk bf16 packing.
//
// ws layout: ykv bf16 [65536][256] @0 (32MB) | q bf16 [65536][128] @32M (16MB)
//            | whi[512][128] @48M (128KB) | wlo (128KB).

typedef float f32x4 __attribute__((ext_vector_type(4)));
typedef short s16x4 __attribute__((ext_vector_type(4)));
typedef short s16x8 __attribute__((ext_vector_type(8)));
typedef unsigned int u32x2 __attribute__((ext_vector_type(2)));

__device__ inline ushort f2bf(float f) {   // RNE float->bf16 (cold paths)
    unsigned u = __float_as_uint(f);
    return (ushort)((u + 0x7FFF + ((u >> 16) & 1)) >> 16);
}
__device__ inline float bf2f(ushort h) { return __uint_as_float((unsigned)h << 16); }
__device__ inline unsigned cvtpk(float a, float b) {   // D[15:0]=bf16(a), D[31:16]=bf16(b)
    unsigned r;
    asm("v_cvt_pk_bf16_f32 %0, %1, %2" : "=v"(r) : "v"(a), "v"(b));
    return r;
}
#if __has_builtin(__builtin_amdgcn_exp2f)
#define EXP2(x) __builtin_amdgcn_exp2f(x)
#else
#define EXP2(x) exp2f(x)
#endif

// PV mfma (16x16x16): builtin if present, else fenced inline asm (R4-verified).
#if __has_builtin(__builtin_amdgcn_mfma_f32_16x16x16bf16_1k)
#define MFMA16(d, a, b) \
    d = __builtin_amdgcn_mfma_f32_16x16x16bf16_1k(a, b, d, 0, 0, 0)
#define MFMA_FENCE() ((void)0)
#else
#define MFMA16(d, a, b) \
    asm volatile("v_mfma_f32_16x16x16_bf16 %0, %1, %2, %0" \
                 : "+v"(d) : "v"(a), "v"(b))
#define MFMA_FENCE() do {                                   \
    __builtin_amdgcn_sched_barrier(0);                      \
    asm volatile("s_nop 7\n\ts_nop 7" ::: "memory");        \
    __builtin_amdgcn_sched_barrier(0);                      \
} while (0)
#endif

// ---------------------------------------------------------------------------
// Weight split: rows 0-127 q_w, 128-383 kv_w, 384-511 proj_w. 65536 elems.
__global__ __launch_bounds__(256) void conv_w(
    const float* __restrict__ q_w, const float* __restrict__ kv_w,
    const float* __restrict__ proj_w, ushort* whi, ushort* wlo)
{
    const int g = blockIdx.x * 256 + threadIdx.x;      // 0..65535
    const int row = g >> 7, col = g & 127;
    const float v = (row < 128) ? q_w[row * 128 + col]
                  : (row < 384) ? kv_w[(row - 128) * 128 + col]
                                : proj_w[(row - 384) * 128 + col];
    const ushort h = f2bf(v);
    whi[g] = h;
    wlo[g] = f2bf(v - bf2f(h));
}

// ---------------------------------------------------------------------------
// Split-bf16 MFMA GEMM: C[row0..+127][chan] = A(fp32) @ W^T (+bias).
// Swapped operands: mfma(A=w_frag, B=x_frag) -> lane(l&15)=pixel holds 4
// consecutive chans. A-tile (full K=128) split hi/lo into swizzled LDS once
// per block; W-frags from global (L2-hot). 4 waves = 2x2 of 64x64.
__global__ __launch_bounds__(256, 2) void gemm_split(
    const float* A,                                   // [M][128] fp32
    const ushort* __restrict__ Whi, const ushort* __restrict__ Wlo,
    int wbase, int ntc, int tok1,
    ushort* qb, ushort* kvb, float* outf, const float* __restrict__ bias)
{
    __shared__ ushort Ah[128 * 128];   // [row][k] swizzled 16B chunks, 32KB
    __shared__ ushort Al[128 * 128];

    const int t = threadIdx.x;
    const int row0 = blockIdx.x * 128;
    const int w = t >> 6, l = t & 63;
    const int wm = w >> 1, wn = w & 1;
    const int lr = l & 15, cA = l >> 4;

    // ---- stage + split A (coalesced float4; chunk-XOR swizzle: chunk^=(row&7))
#pragma unroll
    for (int i = 0; i < 16; ++i) {
        const int idx = t + i * 256;
        const int p = idx >> 5, fc = idx & 31;         // row, float4-col
        const float4 v = *(const float4*)(A + (size_t)(row0 + p) * 128 + fc * 4);
        const int base = p * 128 + (((fc >> 1) ^ (p & 7)) << 3) + (fc & 1) * 4;
        const unsigned h01 = cvtpk(v.x, v.y), h23 = cvtpk(v.z, v.w);
        *(u32x2*)&Ah[base] = (u32x2){h01, h23};
        const float hx = __uint_as_float(h01 << 16);
        const float hy = __uint_as_float(h01 & 0xFFFF0000u);
        const float hz = __uint_as_float(h23 << 16);
        const float hw = __uint_as_float(h23 & 0xFFFF0000u);
        *(u32x2*)&Al[base] = (u32x2){ cvtpk(v.x - hx, v.y - hy),
                                      cvtpk(v.z - hz, v.w - hw) };
    }
    __syncthreads();

#pragma unroll 1
    for (int nt = 0; nt < ntc; ++nt) {
        f32x4 acc[4][4];                               // [mf][nf]
#pragma unroll
        for (int mf = 0; mf < 4; ++mf)
#pragma unroll
            for (int nf = 0; nf < 4; ++nf) acc[mf][nf] = (f32x4){0.f,0.f,0.f,0.f};

#pragma unroll
        for (int kk = 0; kk < 4; ++kk) {
            s16x8 xh[4], xl[4], wh[4], wl[4];
#pragma unroll
            for (int mf = 0; mf < 4; ++mf) {
                const int p = wm * 64 + mf * 16 + lr;
                const int off = p * 128 + ((((kk << 2) + cA) ^ (p & 7)) << 3);
                xh[mf] = *(const s16x8*)&Ah[off];
                xl[mf] = *(const s16x8*)&Al[off];
            }
#pragma unroll
            for (int nf = 0; nf < 4; ++nf) {
                const size_t off = (size_t)(wbase + nt * 128 + wn * 64 + nf * 16 + lr) * 128
                                 + kk * 32 + cA * 8;
                wh[nf] = *(const s16x8*)&Whi[off];
                wl[nf] = *(const s16x8*)&Wlo[off];
            }
#pragma unroll
            for (int nf = 0; nf < 4; ++nf)
#pragma unroll
                for (int mf = 0; mf < 4; ++mf) {
                    acc[mf][nf] = __builtin_amdgcn_mfma_f32_16x16x32_bf16(
                                      wh[nf], xh[mf], acc[mf][nf], 0, 0, 0);
                    acc[mf][nf] = __builtin_amdgcn_mfma_f32_16x16x32_bf16(
                                      wh[nf], xl[mf], acc[mf][nf], 0, 0, 0);
                    acc[mf][nf] = __builtin_amdgcn_mfma_f32_16x16x32_bf16(
                                      wl[nf], xh[mf], acc[mf][nf], 0, 0, 0);
                }
        }

        // ---- store: pixel = row0+wm*64+mf*16+lr, chan = wn*64+nf*16+cA*4+r
#pragma unroll
        for (int mf = 0; mf < 4; ++mf) {
            const size_t pix = row0 + wm * 64 + mf * 16 + lr;
#pragma unroll
            for (int nf = 0; nf < 4; ++nf) {
                const int chan = wn * 64 + nf * 16 + cA * 4;
                const f32x4 o = acc[mf][nf];
                if (tok1) {
                    const u32x2 pk = (u32x2){ cvtpk(o[0], o[1]), cvtpk(o[2], o[3]) };
                    if (nt == 0) *(u32x2*)(qb + pix * 128 + chan) = pk;
                    else         *(u32x2*)(kvb + pix * 256 + (nt - 1) * 128 + chan) = pk;
                } else {
                    const float4 bv = *(const float4*)(bias + chan);
                    f32x4 r = o;
                    r[0] += bv.x; r[1] += bv.y; r[2] += bv.z; r[3] += bv.w;
                    *(f32x4*)(outf + pix * 128 + chan) = r;
                }
            }
        }
    }
}

// ---------------------------------------------------------------------------
// MFMA halo attention. grid(256 spatial, 4 batch, 8 head), 256 thr = 4 waves.
// Wave w owns queries w*16..w*16+15 of its block's head. QK (swapped):
// S^T = K·Q^T via mfma_f32_16x16x32_bf16 (d=16 zero-padded in qf only; ak
// loads unconditionally — upper-K lanes multiply qf=0). C-frag (col=q=l&15,
// row=key=(l>>4)*4+r) == B-frag of the 16x16x16 PV mfma.
// Mask folded into bias table: invalid keys gather sentinel -3e4 -> exp2=0.
__global__ __launch_bounds__(256) void halo_attn(
    float* out,                           // d_out fp32 (65536 x 128)
    const ushort* __restrict__ qg,        // ws q bf16 (65536 x 128)
    const ushort* __restrict__ kvg,       // ws kv bf16 (65536 x 256): h: k h*32, v h*32+16
    const float* __restrict__ pos_table)  // (729, 8)
{
    __shared__ ushort VT[16][216];        // [dim][key] bf16 (pad 208->216)  6912 B
    __shared__ float  bias_l[648];        // [0,441): bias*log2e; [441,648): -3e4 sentinel
    __shared__ int    keyoff[208];        // byte offset into kv (0 if invalid)
    __shared__ short  koff2[208];         // ky*21+kx, or -200 (sentinel) if invalid

    const int t  = threadIdx.x;
    const int bi = blockIdx.x, b = blockIdx.y, head = blockIdx.z;
    const int by = bi >> 4, bx = bi & 15;
    const int w  = t >> 6;                 // wave id = q-tile
    const int l  = t & 63;
    const int lr = l & 15;
    const int cA = l >> 4;

    const char* kvb = (const char*)kvg + (size_t)b * (128 * 128 * 256 * 2);

    // ---- per-block LUTs
    if (t < 208) {
        const int wy = t / 14, wx = t - (t / 14) * 14;
        const int py = by * 8 + wy - 3, px = bx * 8 + wx - 3;
        const bool valid = (t < 196) && ((unsigned)py < 128u) && ((unsigned)px < 128u);
        keyoff[t] = valid ? ((py * 128 + px) * 512) : 0;
        koff2[t]  = valid ? (short)(wy * 21 + wx) : (short)(-200);
    }
    for (int i = t; i < 648; i += 256) {
        if (i < 441) {
            const int ry = i / 21, rx = i - ry * 21;
            bias_l[i] = pos_table[((ry + 3) * 27 + rx + 3) * 8 + head] * 1.44269504f;
        } else {
            bias_l[i] = -30000.0f;         // sentinel: exp2 -> 0
        }
    }
    __syncthreads();

    // ---- stage V^T for this head (threads 0..103, 2 keys each)
    if (t < 104) {
        const char* base = kvb + head * 64 + 32;
        const char* s0 = base + keyoff[2 * t];
        const char* s1 = base + keyoff[2 * t + 1];
        const s16x8 a0 = *(const s16x8*)s0;
        const s16x8 a1 = *(const s16x8*)(s0 + 16);
        const s16x8 c0 = *(const s16x8*)s1;
        const s16x8 c1 = *(const s16x8*)(s1 + 16);
#pragma unroll
        for (int j = 0; j < 8; ++j) {
            *(unsigned*)&VT[j][2 * t]     = ((unsigned)(ushort)c0[j] << 16) | (ushort)a0[j];
            *(unsigned*)&VT[j + 8][2 * t] = ((unsigned)(ushort)c1[j] << 16) | (ushort)a1[j];
        }
    }
    __syncthreads();

    // ---- per-wave setup: q = w*16 + lr
    const int q  = w * 16 + lr;
    const int qy = q >> 3, qx = q & 7;
    const size_t pix = ((size_t)(b * 128 + by * 8 + qy)) * 128 + bx * 8 + qx;
    float* optr = out + pix * 128 + head * 16 + cA * 4;
    const int qoff2 = (qy + 13) * 21 + (qx + 13);

    s16x8 qf;
#pragma unroll
    for (int j = 0; j < 8; ++j) qf[j] = 0;
    if (cA < 2)
        qf = *(const s16x8*)(qg + pix * 128 + head * 16 + cA * 8);

    f32x4 accv = (f32x4){0.f, 0.f, 0.f, 0.f};
    float sumf = 0.f;

#pragma unroll 1
    for (int kt = 0; kt < 13; ++kt) {
        // Unconditional A-frag load: lanes cA>=2 read V bytes (in-bounds),
        // which multiply qf=0 -> zero contribution.
        const s16x8 ak = *(const s16x8*)(kvb + keyoff[kt * 16 + lr]
                                         + head * 64 + cA * 16);

        f32x4 sf = __builtin_amdgcn_mfma_f32_16x16x32_bf16(
                       ak, qf, (f32x4){0.f, 0.f, 0.f, 0.f}, 0, 0, 0);

        const int kb = kt * 16 + cA * 4;
        const s16x4 kk = *(const s16x4*)&koff2[kb];
        const s16x4 vt = *(const s16x4*)&VT[lr][kb];

        float pr[4];
#pragma unroll
        for (int r = 0; r < 4; ++r) {
            const int idx = qoff2 - (int)kk[r];
            pr[r] = EXP2(fmaf(sf[r], 0.36067376f, bias_l[idx]));
        }
        sumf += (pr[0] + pr[1]) + (pr[2] + pr[3]);

        u32x2 pk;
        pk[0] = cvtpk(pr[0], pr[1]);
        pk[1] = cvtpk(pr[2], pr[3]);
        const s16x4 pb = *(const s16x4*)&pk;
        MFMA_FENCE();
        MFMA16(accv, vt, pb);
    }
    MFMA_FENCE();

    // ---- reduce sum over cA groups (lanes lr, lr+16, lr+32, lr+48 share q)
    float s = sumf;
    s += __shfl_xor(s, 16);
    s += __shfl_xor(s, 32);
    const float inv = 1.0f / s;
    *(f32x4*)optr = accv * inv;
}

// ---------------------------------------------------------------------------
extern "C" void kernel_launch(void* const* d_in, const int* in_sizes, int n_in,
                              void* d_out, int out_size, void* d_ws, size_t ws_size,
                              hipStream_t stream) {
    const float* x      = (const float*)d_in[0];
    const float* q_w    = (const float*)d_in[1];
    const float* kv_w   = (const float*)d_in[2];
    const float* pt     = (const float*)d_in[3];
    const float* proj_w = (const float*)d_in[4];
    const float* proj_b = (const float*)d_in[5];
    float* out = (float*)d_out;

    ushort* ykvb = (ushort*)d_ws;                                   // 32 MB
    ushort* qb   = (ushort*)((char*)d_ws + 33554432);               // 16 MB
    ushort* whi  = (ushort*)((char*)d_ws + 33554432 + 16777216);    // 128 KB
    ushort* wlo  = whi + 65536;                                     // 128 KB

    const dim3 blk(256);
    conv_w<<<dim3(256), blk, 0, stream>>>(q_w, kv_w, proj_w, whi, wlo);
    gemm_split<<<dim3(512), blk, 0, stream>>>(x, whi, wlo, 0, 3, 1,
                                              qb, ykvb, nullptr, nullptr);
    halo_attn<<<dim3(256, 4, 8), blk, 0, stream>>>(out, qb, ykvb, pt);
    gemm_split<<<dim3(512), blk, 0, stream>>>(out, whi, wlo, 384, 1, 0,
                                              nullptr, nullptr, out, proj_b);
}

// Round 9
// 137.593 us; speedup vs baseline: 1.0091x; 1.0091x over previous
//
#include <hip/hip_runtime.h>
#include <float.h>

// HaloAttn: x(4,128,128,128) f32 -> out(4,128,128,128) f32
// BS=8, HS=3, WIN=14, NH=8, DQK=DV=16, SCALE=0.25
//
// k0: conv_w      q_w|kv_w|proj_w (512x128 f32) -> hi/lo bf16 in ws
// k1: gemm_split  q=x@q_w^T -> ws bf16, kv=x@kv_w^T -> ws bf16   (3-term split MFMA)
// k2: halo_attn   1 head/block (grid.z=8), 1 q-tile/wave; ALL-builtin K=32 MFMA:
//                 QK with permuted key order so paired C-frags == PV B-frag
// k3: gemm_split  d_out = d_out @ proj_w^T + proj_b (in place, split MFMA)
//
// Key permutation (pair m, sub-tile s, A-row i): global key g = 32m + (i>>2)*8 + 4s + (i&3).
// QK C-frag -> lane(lr,cA) holds S for keys 32m + cA*8 + 4s + r  (r=0..3).
// PV B-frag (16x16x32) needs keys 32m + cA*8 + j (j=0..7) = s=0 then s=1 -> concat, no shuffles.
//
// ws layout: ykv bf16 [65536][256] @0 (32MB) | q bf16 [65536][128] @32M (16MB)
//            | whi[512][128] @48M (128KB) | wlo (128KB).

typedef float f32x4 __attribute__((ext_vector_type(4)));
typedef short s16x4 __attribute__((ext_vector_type(4)));
typedef short s16x8 __attribute__((ext_vector_type(8)));
typedef unsigned int u32x2 __attribute__((ext_vector_type(2)));
typedef unsigned int u32x4 __attribute__((ext_vector_type(4)));

__device__ inline ushort f2bf(float f) {   // RNE float->bf16 (cold paths)
    unsigned u = __float_as_uint(f);
    return (ushort)((u + 0x7FFF + ((u >> 16) & 1)) >> 16);
}
__device__ inline float bf2f(ushort h) { return __uint_as_float((unsigned)h << 16); }
__device__ inline unsigned cvtpk(float a, float b) {   // D[15:0]=bf16(a), D[31:16]=bf16(b)
    unsigned r;
    asm("v_cvt_pk_bf16_f32 %0, %1, %2" : "=v"(r) : "v"(a), "v"(b));
    return r;
}
#if __has_builtin(__builtin_amdgcn_exp2f)
#define EXP2(x) __builtin_amdgcn_exp2f(x)
#else
#define EXP2(x) exp2f(x)
#endif

// ---------------------------------------------------------------------------
// Weight split: rows 0-127 q_w, 128-383 kv_w, 384-511 proj_w. 65536 elems.
__global__ __launch_bounds__(256) void conv_w(
    const float* __restrict__ q_w, const float* __restrict__ kv_w,
    const float* __restrict__ proj_w, ushort* whi, ushort* wlo)
{
    const int g = blockIdx.x * 256 + threadIdx.x;      // 0..65535
    const int row = g >> 7, col = g & 127;
    const float v = (row < 128) ? q_w[row * 128 + col]
                  : (row < 384) ? kv_w[(row - 128) * 128 + col]
                                : proj_w[(row - 384) * 128 + col];
    const ushort h = f2bf(v);
    whi[g] = h;
    wlo[g] = f2bf(v - bf2f(h));
}

// ---------------------------------------------------------------------------
// Split-bf16 MFMA GEMM: C[row0..+127][chan] = A(fp32) @ W^T (+bias).
// Swapped operands: mfma(A=w_frag, B=x_frag) -> lane(l&15)=pixel holds 4
// consecutive chans. A-tile (full K=128) split hi/lo into swizzled LDS once
// per block; W-frags from global (L2-hot). 4 waves = 2x2 of 64x64.
__global__ __launch_bounds__(256, 2) void gemm_split(
    const float* A,                                   // [M][128] fp32
    const ushort* __restrict__ Whi, const ushort* __restrict__ Wlo,
    int wbase, int ntc, int tok1,
    ushort* qb, ushort* kvb, float* outf, const float* __restrict__ bias)
{
    __shared__ ushort Ah[128 * 128];   // [row][k] swizzled 16B chunks, 32KB
    __shared__ ushort Al[128 * 128];

    const int t = threadIdx.x;
    const int row0 = blockIdx.x * 128;
    const int w = t >> 6, l = t & 63;
    const int wm = w >> 1, wn = w & 1;
    const int lr = l & 15, cA = l >> 4;

    // ---- stage + split A (coalesced float4; chunk-XOR swizzle: chunk^=(row&7))
#pragma unroll
    for (int i = 0; i < 16; ++i) {
        const int idx = t + i * 256;
        const int p = idx >> 5, fc = idx & 31;         // row, float4-col
        const float4 v = *(const float4*)(A + (size_t)(row0 + p) * 128 + fc * 4);
        const int base = p * 128 + (((fc >> 1) ^ (p & 7)) << 3) + (fc & 1) * 4;
        const unsigned h01 = cvtpk(v.x, v.y), h23 = cvtpk(v.z, v.w);
        *(u32x2*)&Ah[base] = (u32x2){h01, h23};
        const float hx = __uint_as_float(h01 << 16);
        const float hy = __uint_as_float(h01 & 0xFFFF0000u);
        const float hz = __uint_as_float(h23 << 16);
        const float hw = __uint_as_float(h23 & 0xFFFF0000u);
        *(u32x2*)&Al[base] = (u32x2){ cvtpk(v.x - hx, v.y - hy),
                                      cvtpk(v.z - hz, v.w - hw) };
    }
    __syncthreads();

#pragma unroll 1
    for (int nt = 0; nt < ntc; ++nt) {
        f32x4 acc[4][4];                               // [mf][nf]
#pragma unroll
        for (int mf = 0; mf < 4; ++mf)
#pragma unroll
            for (int nf = 0; nf < 4; ++nf) acc[mf][nf] = (f32x4){0.f,0.f,0.f,0.f};

#pragma unroll
        for (int kk = 0; kk < 4; ++kk) {
            s16x8 xh[4], xl[4], wh[4], wl[4];
#pragma unroll
            for (int mf = 0; mf < 4; ++mf) {
                const int p = wm * 64 + mf * 16 + lr;
                const int off = p * 128 + ((((kk << 2) + cA) ^ (p & 7)) << 3);
                xh[mf] = *(const s16x8*)&Ah[off];
                xl[mf] = *(const s16x8*)&Al[off];
            }
#pragma unroll
            for (int nf = 0; nf < 4; ++nf) {
                const size_t off = (size_t)(wbase + nt * 128 + wn * 64 + nf * 16 + lr) * 128
                                 + kk * 32 + cA * 8;
                wh[nf] = *(const s16x8*)&Whi[off];
                wl[nf] = *(const s16x8*)&Wlo[off];
            }
#pragma unroll
            for (int nf = 0; nf < 4; ++nf)
#pragma unroll
                for (int mf = 0; mf < 4; ++mf) {
                    acc[mf][nf] = __builtin_amdgcn_mfma_f32_16x16x32_bf16(
                                      wh[nf], xh[mf], acc[mf][nf], 0, 0, 0);
                    acc[mf][nf] = __builtin_amdgcn_mfma_f32_16x16x32_bf16(
                                      wh[nf], xl[mf], acc[mf][nf], 0, 0, 0);
                    acc[mf][nf] = __builtin_amdgcn_mfma_f32_16x16x32_bf16(
                                      wl[nf], xh[mf], acc[mf][nf], 0, 0, 0);
                }
        }

        // ---- store: pixel = row0+wm*64+mf*16+lr, chan = wn*64+nf*16+cA*4+r
#pragma unroll
        for (int mf = 0; mf < 4; ++mf) {
            const size_t pix = row0 + wm * 64 + mf * 16 + lr;
#pragma unroll
            for (int nf = 0; nf < 4; ++nf) {
                const int chan = wn * 64 + nf * 16 + cA * 4;
                const f32x4 o = acc[mf][nf];
                if (tok1) {
                    const u32x2 pk = (u32x2){ cvtpk(o[0], o[1]), cvtpk(o[2], o[3]) };
                    if (nt == 0) *(u32x2*)(qb + pix * 128 + chan) = pk;
                    else         *(u32x2*)(kvb + pix * 256 + (nt - 1) * 128 + chan) = pk;
                } else {
                    const float4 bv = *(const float4*)(bias + chan);
                    f32x4 r = o;
                    r[0] += bv.x; r[1] += bv.y; r[2] += bv.z; r[3] += bv.w;
                    *(f32x4*)(outf + pix * 128 + chan) = r;
                }
            }
        }
    }
}

// ---------------------------------------------------------------------------
// MFMA halo attention. grid(256 spatial, 4 batch, 8 head), 256 thr = 4 waves.
// Wave w owns queries w*16..w*16+15. 7 key-pairs x {2 QK + 1 PV}, all
// mfma_f32_16x16x32_bf16. Keys 196..223 padded via sentinel bias (p=0).
__global__ __launch_bounds__(256) void halo_attn(
    float* out,                           // d_out fp32 (65536 x 128)
    const ushort* __restrict__ qg,        // ws q bf16 (65536 x 128)
    const ushort* __restrict__ kvg,       // ws kv bf16 (65536 x 256): h: k h*32, v h*32+16
    const float* __restrict__ pos_table)  // (729, 8)
{
    __shared__ ushort VT[16][232];        // [dim][global key] bf16, stride 232 (16B-align, odd/8)
    __shared__ float  bias_l[648];        // [0,441): bias*log2e; [441,648): -3e4 sentinel
    __shared__ int    keyoff[256];        // byte offset into kv (0 if invalid/pad)
    __shared__ short  koff2[224];         // ky*21+kx, or -200 (sentinel) if invalid

    const int t  = threadIdx.x;
    const int bi = blockIdx.x, b = blockIdx.y, head = blockIdx.z;
    const int by = bi >> 4, bx = bi & 15;
    const int w  = t >> 6;                 // wave id = q-tile
    const int l  = t & 63;
    const int lr = l & 15;
    const int cA = l >> 4;

    const char* kvb = (const char*)kvg + (size_t)b * (128 * 128 * 256 * 2);

    // ---- per-block LUTs (keys 196..223 are pad; keyoff 224..255 prefetch pad)
    if (t < 224) {
        const int wy = t / 14, wx = t - (t / 14) * 14;
        const int py = by * 8 + wy - 3, px = bx * 8 + wx - 3;
        const bool valid = (t < 196) && ((unsigned)py < 128u) && ((unsigned)px < 128u);
        keyoff[t] = valid ? ((py * 128 + px) * 512) : 0;
        koff2[t]  = valid ? (short)(wy * 21 + wx) : (short)(-200);
    } else {
        keyoff[t] = 0;
    }
    for (int i = t; i < 648; i += 256) {
        if (i < 441) {
            const int ry = i / 21, rx = i - ry * 21;
            bias_l[i] = pos_table[((ry + 3) * 27 + rx + 3) * 8 + head] * 1.44269504f;
        } else {
            bias_l[i] = -30000.0f;         // sentinel: exp2 -> 0
        }
    }
    __syncthreads();

    // ---- stage V^T (global key order) for this head: threads 0..111, 2 keys each
    if (t < 112) {
        const char* base = kvb + head * 64 + 32;
        const char* s0 = base + keyoff[2 * t];
        const char* s1 = base + keyoff[2 * t + 1];
        const s16x8 a0 = *(const s16x8*)s0;
        const s16x8 a1 = *(const s16x8*)(s0 + 16);
        const s16x8 c0 = *(const s16x8*)s1;
        const s16x8 c1 = *(const s16x8*)(s1 + 16);
#pragma unroll
        for (int j = 0; j < 8; ++j) {
            *(unsigned*)&VT[j][2 * t]     = ((unsigned)(ushort)c0[j] << 16) | (ushort)a0[j];
            *(unsigned*)&VT[j + 8][2 * t] = ((unsigned)(ushort)c1[j] << 16) | (ushort)a1[j];
        }
    }
    __syncthreads();

    // ---- per-wave setup: q = w*16 + lr
    const int q  = w * 16 + lr;
    const int qy = q >> 3, qx = q & 7;
    const size_t pix = ((size_t)(b * 128 + by * 8 + qy)) * 128 + bx * 8 + qx;
    float* optr = out + pix * 128 + head * 16 + cA * 4;
    const int qoff2 = (qy + 13) * 21 + (qx + 13);
    const int gbase = ((lr >> 2) << 3) + (lr & 3);   // key-permutation base for A-row lr

    s16x8 qf;
#pragma unroll
    for (int j = 0; j < 8; ++j) qf[j] = 0;
    if (cA < 2)
        qf = *(const s16x8*)(qg + pix * 128 + head * 16 + cA * 8);

    f32x4 accv = (f32x4){0.f, 0.f, 0.f, 0.f};
    float sumf = 0.f;

    const char* kvh = kvb + head * 64;
    // prefetch pair 0 (lanes cA>=2 read V bytes; they multiply qf=0)
    s16x8 ak0 = *(const s16x8*)(kvh + keyoff[gbase]     + cA * 16);
    s16x8 ak1 = *(const s16x8*)(kvh + keyoff[gbase + 4] + cA * 16);

#pragma unroll 1
    for (int m = 0; m < 7; ++m) {
        const f32x4 sf0 = __builtin_amdgcn_mfma_f32_16x16x32_bf16(
                              ak0, qf, (f32x4){0.f, 0.f, 0.f, 0.f}, 0, 0, 0);
        const f32x4 sf1 = __builtin_amdgcn_mfma_f32_16x16x32_bf16(
                              ak1, qf, (f32x4){0.f, 0.f, 0.f, 0.f}, 0, 0, 0);

        // prefetch pair m+1 (keyoff padded to 256 -> always in-bounds)
        const int nx = 32 * (m + 1) + gbase;
        ak0 = *(const s16x8*)(kvh + keyoff[nx]     + cA * 16);
        ak1 = *(const s16x8*)(kvh + keyoff[nx + 4] + cA * 16);

        const int kb = 32 * m + cA * 8;                // this lane's 8 global keys
        const s16x8 kk = *(const s16x8*)&koff2[kb];
        const s16x8 vt = *(const s16x8*)&VT[lr][kb];   // PV A-frag (dim=lr)

        float pr0[4], pr1[4];
#pragma unroll
        for (int r = 0; r < 4; ++r)
            pr0[r] = EXP2(fmaf(sf0[r], 0.36067376f, bias_l[qoff2 - (int)kk[r]]));
#pragma unroll
        for (int r = 0; r < 4; ++r)
            pr1[r] = EXP2(fmaf(sf1[r], 0.36067376f, bias_l[qoff2 - (int)kk[4 + r]]));
        sumf += ((pr0[0] + pr0[1]) + (pr0[2] + pr0[3]))
              + ((pr1[0] + pr1[1]) + (pr1[2] + pr1[3]));

        const u32x4 pk = (u32x4){ cvtpk(pr0[0], pr0[1]), cvtpk(pr0[2], pr0[3]),
                                  cvtpk(pr1[0], pr1[1]), cvtpk(pr1[2], pr1[3]) };
        const s16x8 pb = *(const s16x8*)&pk;           // PV B-frag: keys cA*8+0..7
        accv = __builtin_amdgcn_mfma_f32_16x16x32_bf16(vt, pb, accv, 0, 0, 0);
    }

    // ---- reduce sum over cA groups (lanes lr, lr+16, lr+32, lr+48 share q)
    float s = sumf;
    s += __shfl_xor(s, 16);
    s += __shfl_xor(s, 32);
    const float inv = 1.0f / s;
    *(f32x4*)optr = accv * inv;
}

// ---------------------------------------------------------------------------
extern "C" void kernel_launch(void* const* d_in, const int* in_sizes, int n_in,
                              void* d_out, int out_size, void* d_ws, size_t ws_size,
                              hipStream_t stream) {
    const float* x      = (const float*)d_in[0];
    const float* q_w    = (const float*)d_in[1];
    const float* kv_w   = (const float*)d_in[2];
    const float* pt     = (const float*)d_in[3];
    const float* proj_w = (const float*)d_in[4];
    const float* proj_b = (const float*)d_in[5];
    float* out = (float*)d_out;

    ushort* ykvb = (ushort*)d_ws;                                   // 32 MB
    ushort* qb   = (ushort*)((char*)d_ws + 33554432);               // 16 MB
    ushort* whi  = (ushort*)((char*)d_ws + 33554432 + 16777216);    // 128 KB
    ushort* wlo  = whi + 65536;                                     // 128 KB

    const dim3 blk(256);
    conv_w<<<dim3(256), blk, 0, stream>>>(q_w, kv_w, proj_w, whi, wlo);
    gemm_split<<<dim3(512), blk, 0, stream>>>(x, whi, wlo, 0, 3, 1,
                                              qb, ykvb, nullptr, nullptr);
    halo_attn<<<dim3(256, 4, 8), blk, 0, stream>>>(out, qb, ykvb, pt);
    gemm_split<<<dim3(512), blk, 0, stream>>>(out, whi, wlo, 384, 1, 0,
                                              nullptr, nullptr, out, proj_b);
}

// Round 10
// 121.445 us; speedup vs baseline: 1.1433x; 1.1330x over previous
//
#include <hip/hip_runtime.h>
#include <float.h>

// HaloAttn: x(4,128,128,128) f32 -> out(4,128,128,128) f32
// BS=8, HS=3, WIN=14, NH=8, DQK=DV=16, SCALE=0.25
//
// k0: conv_w      q_w|kv_w|proj_w (512x128 f32) -> hi/lo bf16 in ws
// k1: gemm_split  q=x@q_w^T -> ws bf16, kv=x@kv_w^T -> ws bf16   (3-term split MFMA)
// k2: halo_attn   block=(spatial,head), wave=batch, 4 q-tiles/wave; all-builtin
//                 K=32 MFMA, permuted key order (QK C-frags concat == PV B-frag)
// k3: gemm_split  d_out = d_out @ proj_w^T + proj_b (in place, split MFMA)
//
// Key permutation (pair m, sub-tile s, A-row i): global key g = 32m + (i>>2)*8 + 4s + (i&3).
// QK C-frag -> lane(lr,cA) holds S for keys 32m + cA*8 + 4s + r  (r=0..3).
// PV B-frag (16x16x32) needs keys 32m + cA*8 + j (j=0..7) -> concat s=0,s=1. No shuffles.
//
// ws layout: ykv bf16 [65536][256] @0 (32MB) | q bf16 [65536][128] @32M (16MB)
//            | whi[512][128] @48M (128KB) | wlo (128KB).

typedef float f32x4 __attribute__((ext_vector_type(4)));
typedef short s16x4 __attribute__((ext_vector_type(4)));
typedef short s16x8 __attribute__((ext_vector_type(8)));
typedef unsigned int u32x2 __attribute__((ext_vector_type(2)));
typedef unsigned int u32x4 __attribute__((ext_vector_type(4)));

__device__ inline ushort f2bf(float f) {   // RNE float->bf16 (cold paths)
    unsigned u = __float_as_uint(f);
    return (ushort)((u + 0x7FFF + ((u >> 16) & 1)) >> 16);
}
__device__ inline float bf2f(ushort h) { return __uint_as_float((unsigned)h << 16); }
__device__ inline unsigned cvtpk(float a, float b) {   // D[15:0]=bf16(a), D[31:16]=bf16(b)
    unsigned r;
    asm("v_cvt_pk_bf16_f32 %0, %1, %2" : "=v"(r) : "v"(a), "v"(b));
    return r;
}
#if __has_builtin(__builtin_amdgcn_exp2f)
#define EXP2(x) __builtin_amdgcn_exp2f(x)
#else
#define EXP2(x) exp2f(x)
#endif

// ---------------------------------------------------------------------------
// Weight split: rows 0-127 q_w, 128-383 kv_w, 384-511 proj_w. 65536 elems.
__global__ __launch_bounds__(256) void conv_w(
    const float* __restrict__ q_w, const float* __restrict__ kv_w,
    const float* __restrict__ proj_w, ushort* whi, ushort* wlo)
{
    const int g = blockIdx.x * 256 + threadIdx.x;      // 0..65535
    const int row = g >> 7, col = g & 127;
    const float v = (row < 128) ? q_w[row * 128 + col]
                  : (row < 384) ? kv_w[(row - 128) * 128 + col]
                                : proj_w[(row - 384) * 128 + col];
    const ushort h = f2bf(v);
    whi[g] = h;
    wlo[g] = f2bf(v - bf2f(h));
}

// ---------------------------------------------------------------------------
// Split-bf16 MFMA GEMM: C[row0..+127][chan] = A(fp32) @ W^T (+bias).
// Swapped operands: mfma(A=w_frag, B=x_frag) -> lane(l&15)=pixel holds 4
// consecutive chans. A-tile (full K=128) split hi/lo into swizzled LDS once
// per block; W-frags from global (L2-hot). 4 waves = 2x2 of 64x64.
__global__ __launch_bounds__(256, 2) void gemm_split(
    const float* A,                                   // [M][128] fp32
    const ushort* __restrict__ Whi, const ushort* __restrict__ Wlo,
    int wbase, int ntc, int tok1,
    ushort* qb, ushort* kvb, float* outf, const float* __restrict__ bias)
{
    __shared__ ushort Ah[128 * 128];   // [row][k] swizzled 16B chunks, 32KB
    __shared__ ushort Al[128 * 128];

    const int t = threadIdx.x;
    const int row0 = blockIdx.x * 128;
    const int w = t >> 6, l = t & 63;
    const int wm = w >> 1, wn = w & 1;
    const int lr = l & 15, cA = l >> 4;

    // ---- stage + split A (coalesced float4; chunk-XOR swizzle: chunk^=(row&7))
#pragma unroll
    for (int i = 0; i < 16; ++i) {
        const int idx = t + i * 256;
        const int p = idx >> 5, fc = idx & 31;         // row, float4-col
        const float4 v = *(const float4*)(A + (size_t)(row0 + p) * 128 + fc * 4);
        const int base = p * 128 + (((fc >> 1) ^ (p & 7)) << 3) + (fc & 1) * 4;
        const unsigned h01 = cvtpk(v.x, v.y), h23 = cvtpk(v.z, v.w);
        *(u32x2*)&Ah[base] = (u32x2){h01, h23};
        const float hx = __uint_as_float(h01 << 16);
        const float hy = __uint_as_float(h01 & 0xFFFF0000u);
        const float hz = __uint_as_float(h23 << 16);
        const float hw = __uint_as_float(h23 & 0xFFFF0000u);
        *(u32x2*)&Al[base] = (u32x2){ cvtpk(v.x - hx, v.y - hy),
                                      cvtpk(v.z - hz, v.w - hw) };
    }
    __syncthreads();

#pragma unroll 1
    for (int nt = 0; nt < ntc; ++nt) {
        f32x4 acc[4][4];                               // [mf][nf]
#pragma unroll
        for (int mf = 0; mf < 4; ++mf)
#pragma unroll
            for (int nf = 0; nf < 4; ++nf) acc[mf][nf] = (f32x4){0.f,0.f,0.f,0.f};

#pragma unroll
        for (int kk = 0; kk < 4; ++kk) {
            s16x8 xh[4], xl[4], wh[4], wl[4];
#pragma unroll
            for (int mf = 0; mf < 4; ++mf) {
                const int p = wm * 64 + mf * 16 + lr;
                const int off = p * 128 + ((((kk << 2) + cA) ^ (p & 7)) << 3);
                xh[mf] = *(const s16x8*)&Ah[off];
                xl[mf] = *(const s16x8*)&Al[off];
            }
#pragma unroll
            for (int nf = 0; nf < 4; ++nf) {
                const size_t off = (size_t)(wbase + nt * 128 + wn * 64 + nf * 16 + lr) * 128
                                 + kk * 32 + cA * 8;
                wh[nf] = *(const s16x8*)&Whi[off];
                wl[nf] = *(const s16x8*)&Wlo[off];
            }
#pragma unroll
            for (int nf = 0; nf < 4; ++nf)
#pragma unroll
                for (int mf = 0; mf < 4; ++mf) {
                    acc[mf][nf] = __builtin_amdgcn_mfma_f32_16x16x32_bf16(
                                      wh[nf], xh[mf], acc[mf][nf], 0, 0, 0);
                    acc[mf][nf] = __builtin_amdgcn_mfma_f32_16x16x32_bf16(
                                      wh[nf], xl[mf], acc[mf][nf], 0, 0, 0);
                    acc[mf][nf] = __builtin_amdgcn_mfma_f32_16x16x32_bf16(
                                      wl[nf], xh[mf], acc[mf][nf], 0, 0, 0);
                }
        }

        // ---- store: pixel = row0+wm*64+mf*16+lr, chan = wn*64+nf*16+cA*4+r
#pragma unroll
        for (int mf = 0; mf < 4; ++mf) {
            const size_t pix = row0 + wm * 64 + mf * 16 + lr;
#pragma unroll
            for (int nf = 0; nf < 4; ++nf) {
                const int chan = wn * 64 + nf * 16 + cA * 4;
                const f32x4 o = acc[mf][nf];
                if (tok1) {
                    const u32x2 pk = (u32x2){ cvtpk(o[0], o[1]), cvtpk(o[2], o[3]) };
                    if (nt == 0) *(u32x2*)(qb + pix * 128 + chan) = pk;
                    else         *(u32x2*)(kvb + pix * 256 + (nt - 1) * 128 + chan) = pk;
                } else {
                    const float4 bv = *(const float4*)(bias + chan);
                    f32x4 r = o;
                    r[0] += bv.x; r[1] += bv.y; r[2] += bv.z; r[3] += bv.w;
                    *(f32x4*)(outf + pix * 128 + chan) = r;
                }
            }
        }
    }
}

// ---------------------------------------------------------------------------
// MFMA halo attention. grid(256 spatial, 8 head), 256 thr = 4 waves = 4 BATCHES.
// Wave w = batch b: all 64 queries (4 q-tiles) of (b, head, spatial block).
// Per key-pair m: 2 ak gathers -> 8 QK MFMA (x4 q-tiles) + 4 PV MFMA.
// Keys 196..223 padded via sentinel bias (p=0). LUT/bias shared across waves.
__global__ __launch_bounds__(256) void halo_attn(
    float* out,                           // d_out fp32 (65536 x 128)
    const ushort* __restrict__ qg,        // ws q bf16 (65536 x 128)
    const ushort* __restrict__ kvg,       // ws kv bf16 (65536 x 256): h: k h*32, v h*32+16
    const float* __restrict__ pos_table)  // (729, 8)
{
    __shared__ ushort VT[4][16][232];     // [batch][dim][key] bf16, stride 232   29696 B
    __shared__ float  bias_l[648];        // [0,441): bias*log2e; [441,648): sentinel
    __shared__ int    keyoff[256];        // byte offset into kv (0 if invalid/pad)
    __shared__ short  koff2[224];         // ky*21+kx, or -200 (sentinel) if invalid

    const int t  = threadIdx.x;
    const int bi = blockIdx.x, head = blockIdx.y;
    const int by = bi >> 4, bx = bi & 15;
    const int w  = t >> 6;                 // wave id = batch
    const int l  = t & 63;
    const int lr = l & 15;
    const int cA = l >> 4;

    const char* kvb = (const char*)kvg + (size_t)w * (128 * 128 * 256 * 2);

    // ---- per-block LUTs (keys 196..223 pad; keyoff 224..255 prefetch pad)
    if (t < 224) {
        const int wy = t / 14, wx = t - (t / 14) * 14;
        const int py = by * 8 + wy - 3, px = bx * 8 + wx - 3;
        const bool valid = (t < 196) && ((unsigned)py < 128u) && ((unsigned)px < 128u);
        keyoff[t] = valid ? ((py * 128 + px) * 512) : 0;
        koff2[t]  = valid ? (short)(wy * 21 + wx) : (short)(-200);
    } else {
        keyoff[t] = 0;
    }
    for (int i = t; i < 648; i += 256) {
        if (i < 441) {
            const int ry = i / 21, rx = i - ry * 21;
            bias_l[i] = pos_table[((ry + 3) * 27 + rx + 3) * 8 + head] * 1.44269504f;
        } else {
            bias_l[i] = -30000.0f;         // sentinel: exp2 -> 0
        }
    }
    __syncthreads();

    // ---- stage V^T for this wave's batch (each lane: 2-key slots, 16 u32 writes)
    {
        const char* base = kvb + head * 64 + 32;
#pragma unroll 1
        for (int idx = l; idx < 112; idx += 64) {
            const char* s0 = base + keyoff[2 * idx];
            const char* s1 = base + keyoff[2 * idx + 1];
            const s16x8 a0 = *(const s16x8*)s0;
            const s16x8 a1 = *(const s16x8*)(s0 + 16);
            const s16x8 c0 = *(const s16x8*)s1;
            const s16x8 c1 = *(const s16x8*)(s1 + 16);
#pragma unroll
            for (int j = 0; j < 8; ++j) {
                *(unsigned*)&VT[w][j][2 * idx] =
                    ((unsigned)(ushort)c0[j] << 16) | (ushort)a0[j];
                *(unsigned*)&VT[w][j + 8][2 * idx] =
                    ((unsigned)(ushort)c1[j] << 16) | (ushort)a1[j];
            }
        }
    }
    __syncthreads();

    // ---- per-wave setup: 4 q-tiles (q = qt*16 + lr), batch = w
    const int gbase = ((lr >> 2) << 3) + (lr & 3);   // key-permutation base for A-row lr
    s16x8 qf[4];
    float* optr[4];
    int qoff2[4];
#pragma unroll
    for (int qt = 0; qt < 4; ++qt) {
        const int q = qt * 16 + lr;
        const int qy = q >> 3, qx = q & 7;
        const size_t pix = ((size_t)(w * 128 + by * 8 + qy)) * 128 + bx * 8 + qx;
        optr[qt] = out + pix * 128 + head * 16 + cA * 4;
        qoff2[qt] = (qy + 13) * 21 + (qx + 13);
#pragma unroll
        for (int j = 0; j < 8; ++j) qf[qt][j] = 0;
        if (cA < 2)
            qf[qt] = *(const s16x8*)(qg + pix * 128 + head * 16 + cA * 8);
    }

    f32x4 accv[4];
    float sumf[4];
#pragma unroll
    for (int qt = 0; qt < 4; ++qt) {
        accv[qt] = (f32x4){0.f, 0.f, 0.f, 0.f};
        sumf[qt] = 0.f;
    }

    const char* kvh = kvb + head * 64;
    // prefetch pair 0 (lanes cA>=2 read V bytes; they multiply qf=0)
    s16x8 ak0 = *(const s16x8*)(kvh + keyoff[gbase]     + cA * 16);
    s16x8 ak1 = *(const s16x8*)(kvh + keyoff[gbase + 4] + cA * 16);

#pragma unroll 1
    for (int m = 0; m < 7; ++m) {
        // prefetch pair m+1 (keyoff padded to 256 -> always in-bounds)
        const int nx = 32 * (m + 1) + gbase;
        const s16x8 nk0 = *(const s16x8*)(kvh + keyoff[nx]     + cA * 16);
        const s16x8 nk1 = *(const s16x8*)(kvh + keyoff[nx + 4] + cA * 16);

        const int kb = 32 * m + cA * 8;                // this lane's 8 global keys
        const s16x8 kk = *(const s16x8*)&koff2[kb];
        const s16x8 vt = *(const s16x8*)&VT[w][lr][kb];   // PV A-frag (dim=lr)

#pragma unroll
        for (int qt = 0; qt < 4; ++qt) {
            const f32x4 sf0 = __builtin_amdgcn_mfma_f32_16x16x32_bf16(
                                  ak0, qf[qt], (f32x4){0.f, 0.f, 0.f, 0.f}, 0, 0, 0);
            const f32x4 sf1 = __builtin_amdgcn_mfma_f32_16x16x32_bf16(
                                  ak1, qf[qt], (f32x4){0.f, 0.f, 0.f, 0.f}, 0, 0, 0);
            float pr0[4], pr1[4];
#pragma unroll
            for (int r = 0; r < 4; ++r)
                pr0[r] = EXP2(fmaf(sf0[r], 0.36067376f, bias_l[qoff2[qt] - (int)kk[r]]));
#pragma unroll
            for (int r = 0; r < 4; ++r)
                pr1[r] = EXP2(fmaf(sf1[r], 0.36067376f, bias_l[qoff2[qt] - (int)kk[4 + r]]));
            sumf[qt] += ((pr0[0] + pr0[1]) + (pr0[2] + pr0[3]))
                      + ((pr1[0] + pr1[1]) + (pr1[2] + pr1[3]));

            const u32x4 pk = (u32x4){ cvtpk(pr0[0], pr0[1]), cvtpk(pr0[2], pr0[3]),
                                      cvtpk(pr1[0], pr1[1]), cvtpk(pr1[2], pr1[3]) };
            const s16x8 pb = *(const s16x8*)&pk;       // PV B-frag: keys 32m+cA*8+0..7
            accv[qt] = __builtin_amdgcn_mfma_f32_16x16x32_bf16(vt, pb, accv[qt], 0, 0, 0);
        }
        ak0 = nk0;
        ak1 = nk1;
    }

    // ---- reduce sums over cA groups (lanes lr, lr+16, lr+32, lr+48 share q)
#pragma unroll
    for (int qt = 0; qt < 4; ++qt) {
        float s = sumf[qt];
        s += __shfl_xor(s, 16);
        s += __shfl_xor(s, 32);
        const float inv = 1.0f / s;
        *(f32x4*)optr[qt] = accv[qt] * inv;
    }
}

// ---------------------------------------------------------------------------
extern "C" void kernel_launch(void* const* d_in, const int* in_sizes, int n_in,
                              void* d_out, int out_size, void* d_ws, size_t ws_size,
                              hipStream_t stream) {
    const float* x      = (const float*)d_in[0];
    const float* q_w    = (const float*)d_in[1];
    const float* kv_w   = (const float*)d_in[2];
    const float* pt     = (const float*)d_in[3];
    const float* proj_w = (const float*)d_in[4];
    const float* proj_b = (const float*)d_in[5];
    float* out = (float*)d_out;

    ushort* ykvb = (ushort*)d_ws;                                   // 32 MB
    ushort* qb   = (ushort*)((char*)d_ws + 33554432);               // 16 MB
    ushort* whi  = (ushort*)((char*)d_ws + 33554432 + 16777216);    // 128 KB
    ushort* wlo  = whi + 65536;                                     // 128 KB

    const dim3 blk(256);
    conv_w<<<dim3(256), blk, 0, stream>>>(q_w, kv_w, proj_w, whi, wlo);
    gemm_split<<<dim3(512), blk, 0, stream>>>(x, whi, wlo, 0, 3, 1,
                                              qb, ykvb, nullptr, nullptr);
    halo_attn<<<dim3(256, 8), blk, 0, stream>>>(out, qb, ykvb, pt);
    gemm_split<<<dim3(512), blk, 0, stream>>>(out, whi, wlo, 384, 1, 0,
                                              nullptr, nullptr, out, proj_b);
}

// Round 11
// 119.766 us; speedup vs baseline: 1.1593x; 1.0140x over previous
//
#include <hip/hip_runtime.h>
#include <float.h>

// HaloAttn: x(4,128,128,128) f32 -> out(4,128,128,128) f32
// BS=8, HS=3, WIN=14, NH=8, DQK=DV=16, SCALE=0.25
//
// k0: conv_w      q_w|kv_w|proj_w (512x128 f32) -> hi/lo bf16 in ws
// k1: gemm_split  q=x@q_w^T, kv=x@kv_w^T -> ws bf16 in HEAD-MAJOR layout
// k2: halo_attn   block=(spatial,head), wave=batch, 4 q-tiles/wave; all-builtin
//                 K=32 MFMA, permuted key order (QK C-frags concat == PV B-frag)
// k3: gemm_split  d_out = d_out @ proj_w^T + proj_b (in place, split MFMA)
//
// Head-major ws layout (R11): kv[8][65536][32] ushort (k=d0..15, v=d16..31) @0 (32MB)
//   q[8][65536][16] ushort @32M (16MB) | whi[512][128] @48M | wlo (128KB each).
//   One (head,batch) kv slice = 1MB -> L2-resident; window rows = 896B contiguous.
//
// Key permutation (pair m, sub-tile s, A-row i): global key g = 32m + (i>>2)*8 + 4s + (i&3).
// QK C-frag -> lane(lr,cA) holds S for keys 32m + cA*8 + 4s + r  (r=0..3).
// PV B-frag (16x16x32) needs keys 32m + cA*8 + j (j=0..7) -> concat s=0,s=1. No shuffles.

typedef float f32x4 __attribute__((ext_vector_type(4)));
typedef short s16x4 __attribute__((ext_vector_type(4)));
typedef short s16x8 __attribute__((ext_vector_type(8)));
typedef unsigned int u32x2 __attribute__((ext_vector_type(2)));
typedef unsigned int u32x4 __attribute__((ext_vector_type(4)));

__device__ inline ushort f2bf(float f) {   // RNE float->bf16 (cold paths)
    unsigned u = __float_as_uint(f);
    return (ushort)((u + 0x7FFF + ((u >> 16) & 1)) >> 16);
}
__device__ inline float bf2f(ushort h) { return __uint_as_float((unsigned)h << 16); }
__device__ inline unsigned cvtpk(float a, float b) {   // D[15:0]=bf16(a), D[31:16]=bf16(b)
    unsigned r;
    asm("v_cvt_pk_bf16_f32 %0, %1, %2" : "=v"(r) : "v"(a), "v"(b));
    return r;
}
#if __has_builtin(__builtin_amdgcn_exp2f)
#define EXP2(x) __builtin_amdgcn_exp2f(x)
#else
#define EXP2(x) exp2f(x)
#endif

// ---------------------------------------------------------------------------
// Weight split: rows 0-127 q_w, 128-383 kv_w, 384-511 proj_w. 65536 elems.
__global__ __launch_bounds__(256) void conv_w(
    const float* __restrict__ q_w, const float* __restrict__ kv_w,
    const float* __restrict__ proj_w, ushort* whi, ushort* wlo)
{
    const int g = blockIdx.x * 256 + threadIdx.x;      // 0..65535
    const int row = g >> 7, col = g & 127;
    const float v = (row < 128) ? q_w[row * 128 + col]
                  : (row < 384) ? kv_w[(row - 128) * 128 + col]
                                : proj_w[(row - 384) * 128 + col];
    const ushort h = f2bf(v);
    whi[g] = h;
    wlo[g] = f2bf(v - bf2f(h));
}

// ---------------------------------------------------------------------------
// Split-bf16 MFMA GEMM: C[row0..+127][chan] = A(fp32) @ W^T (+bias).
// Swapped operands: mfma(A=w_frag, B=x_frag) -> lane(l&15)=pixel holds 4
// consecutive chans. A-tile (full K=128) split hi/lo into swizzled LDS once
// per block; W-frags from global (L2-hot). 4 waves = 2x2 of 64x64.
// tok1 stores go to HEAD-MAJOR q/kv buffers.
__global__ __launch_bounds__(256, 2) void gemm_split(
    const float* A,                                   // [M][128] fp32
    const ushort* __restrict__ Whi, const ushort* __restrict__ Wlo,
    int wbase, int ntc, int tok1,
    ushort* qb, ushort* kvb, float* outf, const float* __restrict__ bias)
{
    __shared__ ushort Ah[128 * 128];   // [row][k] swizzled 16B chunks, 32KB
    __shared__ ushort Al[128 * 128];

    const int t = threadIdx.x;
    const int row0 = blockIdx.x * 128;
    const int w = t >> 6, l = t & 63;
    const int wm = w >> 1, wn = w & 1;
    const int lr = l & 15, cA = l >> 4;

    // ---- stage + split A (coalesced float4; chunk-XOR swizzle: chunk^=(row&7))
#pragma unroll
    for (int i = 0; i < 16; ++i) {
        const int idx = t + i * 256;
        const int p = idx >> 5, fc = idx & 31;         // row, float4-col
        const float4 v = *(const float4*)(A + (size_t)(row0 + p) * 128 + fc * 4);
        const int base = p * 128 + (((fc >> 1) ^ (p & 7)) << 3) + (fc & 1) * 4;
        const unsigned h01 = cvtpk(v.x, v.y), h23 = cvtpk(v.z, v.w);
        *(u32x2*)&Ah[base] = (u32x2){h01, h23};
        const float hx = __uint_as_float(h01 << 16);
        const float hy = __uint_as_float(h01 & 0xFFFF0000u);
        const float hz = __uint_as_float(h23 << 16);
        const float hw = __uint_as_float(h23 & 0xFFFF0000u);
        *(u32x2*)&Al[base] = (u32x2){ cvtpk(v.x - hx, v.y - hy),
                                      cvtpk(v.z - hz, v.w - hw) };
    }
    __syncthreads();

#pragma unroll 1
    for (int nt = 0; nt < ntc; ++nt) {
        f32x4 acc[4][4];                               // [mf][nf]
#pragma unroll
        for (int mf = 0; mf < 4; ++mf)
#pragma unroll
            for (int nf = 0; nf < 4; ++nf) acc[mf][nf] = (f32x4){0.f,0.f,0.f,0.f};

#pragma unroll
        for (int kk = 0; kk < 4; ++kk) {
            s16x8 xh[4], xl[4], wh[4], wl[4];
#pragma unroll
            for (int mf = 0; mf < 4; ++mf) {
                const int p = wm * 64 + mf * 16 + lr;
                const int off = p * 128 + ((((kk << 2) + cA) ^ (p & 7)) << 3);
                xh[mf] = *(const s16x8*)&Ah[off];
                xl[mf] = *(const s16x8*)&Al[off];
            }
#pragma unroll
            for (int nf = 0; nf < 4; ++nf) {
                const size_t off = (size_t)(wbase + nt * 128 + wn * 64 + nf * 16 + lr) * 128
                                 + kk * 32 + cA * 8;
                wh[nf] = *(const s16x8*)&Whi[off];
                wl[nf] = *(const s16x8*)&Wlo[off];
            }
#pragma unroll
            for (int nf = 0; nf < 4; ++nf)
#pragma unroll
                for (int mf = 0; mf < 4; ++mf) {
                    acc[mf][nf] = __builtin_amdgcn_mfma_f32_16x16x32_bf16(
                                      wh[nf], xh[mf], acc[mf][nf], 0, 0, 0);
                    acc[mf][nf] = __builtin_amdgcn_mfma_f32_16x16x32_bf16(
                                      wh[nf], xl[mf], acc[mf][nf], 0, 0, 0);
                    acc[mf][nf] = __builtin_amdgcn_mfma_f32_16x16x32_bf16(
                                      wl[nf], xh[mf], acc[mf][nf], 0, 0, 0);
                }
        }

        // ---- store: pixel = row0+wm*64+mf*16+lr, chan = wn*64+nf*16+cA*4+r
#pragma unroll
        for (int mf = 0; mf < 4; ++mf) {
            const size_t pix = row0 + wm * 64 + mf * 16 + lr;
#pragma unroll
            for (int nf = 0; nf < 4; ++nf) {
                const int chan = wn * 64 + nf * 16 + cA * 4;
                const f32x4 o = acc[mf][nf];
                if (tok1) {
                    const u32x2 pk = (u32x2){ cvtpk(o[0], o[1]), cvtpk(o[2], o[3]) };
                    if (nt == 0) {
                        // q head-major: q[head][pix][16], head = chan>>4, d = cA*4
                        const int head = wn * 4 + nf;
                        *(u32x2*)(qb + ((size_t)head << 20) + pix * 16 + (chan & 15)) = pk;
                    } else {
                        // kv head-major: kv[head][pix][32], k=d0..15 v=d16..31
                        const int gchan = (nt - 1) * 128 + chan;
                        const int head = gchan >> 5;
                        *(u32x2*)(kvb + ((size_t)head << 21) + pix * 32 + (gchan & 31)) = pk;
                    }
                } else {
                    const float4 bv = *(const float4*)(bias + chan);
                    f32x4 r = o;
                    r[0] += bv.x; r[1] += bv.y; r[2] += bv.z; r[3] += bv.w;
                    *(f32x4*)(outf + pix * 128 + chan) = r;
                }
            }
        }
    }
}

// ---------------------------------------------------------------------------
// MFMA halo attention. grid(256 spatial, 8 head), 256 thr = 4 waves = 4 BATCHES.
// Wave w = batch b: all 64 queries (4 q-tiles) of (b, head, spatial block).
// Per key-pair m: 2 ak gathers -> 8 QK MFMA (x4 q-tiles) + 4 PV MFMA.
// kv head-major: the wave's (head,batch) slice is 1MB -> L2-resident gathers.
__global__ __launch_bounds__(256) void halo_attn(
    float* out,                           // d_out fp32 (65536 x 128)
    const ushort* __restrict__ qg,        // ws q bf16 [8][65536][16] head-major
    const ushort* __restrict__ kvg,       // ws kv bf16 [8][65536][32] head-major
    const float* __restrict__ pos_table)  // (729, 8)
{
    __shared__ ushort VT[4][16][232];     // [batch][dim][key] bf16, stride 232   29696 B
    __shared__ float  bias_l[648];        // [0,441): bias*log2e; [441,648): sentinel
    __shared__ int    keyoff[256];        // byte offset into kv slice (0 if invalid/pad)
    __shared__ short  koff2[224];         // ky*21+kx, or -200 (sentinel) if invalid

    const int t  = threadIdx.x;
    const int bi = blockIdx.x, head = blockIdx.y;
    const int by = bi >> 4, bx = bi & 15;
    const int w  = t >> 6;                 // wave id = batch
    const int l  = t & 63;
    const int lr = l & 15;
    const int cA = l >> 4;

    // this wave's (head, batch) kv slice: 16384 pixels x 64B
    const char* kvh = (const char*)(kvg + ((size_t)head << 21) + ((size_t)w << 19));

    // ---- per-block LUTs (keys 196..223 pad; keyoff 224..255 prefetch pad)
    if (t < 224) {
        const int wy = t / 14, wx = t - (t / 14) * 14;
        const int py = by * 8 + wy - 3, px = bx * 8 + wx - 3;
        const bool valid = (t < 196) && ((unsigned)py < 128u) && ((unsigned)px < 128u);
        keyoff[t] = valid ? ((py * 128 + px) * 64) : 0;    // 64B per pixel record
        koff2[t]  = valid ? (short)(wy * 21 + wx) : (short)(-200);
    } else {
        keyoff[t] = 0;
    }
    for (int i = t; i < 648; i += 256) {
        if (i < 441) {
            const int ry = i / 21, rx = i - ry * 21;
            bias_l[i] = pos_table[((ry + 3) * 27 + rx + 3) * 8 + head] * 1.44269504f;
        } else {
            bias_l[i] = -30000.0f;         // sentinel: exp2 -> 0
        }
    }
    __syncthreads();

    // ---- stage V^T for this wave's batch (each lane: 2-key slots, 16 u32 writes)
    {
        const char* base = kvh + 32;       // v = d16..31 of each record
#pragma unroll 1
        for (int idx = l; idx < 112; idx += 64) {
            const char* s0 = base + keyoff[2 * idx];
            const char* s1 = base + keyoff[2 * idx + 1];
            const s16x8 a0 = *(const s16x8*)s0;
            const s16x8 a1 = *(const s16x8*)(s0 + 16);
            const s16x8 c0 = *(const s16x8*)s1;
            const s16x8 c1 = *(const s16x8*)(s1 + 16);
#pragma unroll
            for (int j = 0; j < 8; ++j) {
                *(unsigned*)&VT[w][j][2 * idx] =
                    ((unsigned)(ushort)c0[j] << 16) | (ushort)a0[j];
                *(unsigned*)&VT[w][j + 8][2 * idx] =
                    ((unsigned)(ushort)c1[j] << 16) | (ushort)a1[j];
            }
        }
    }
    __syncthreads();

    // ---- per-wave setup: 4 q-tiles (q = qt*16 + lr), batch = w
    const int gbase = ((lr >> 2) << 3) + (lr & 3);   // key-permutation base for A-row lr
    const ushort* qh = qg + ((size_t)head << 20);
    s16x8 qf[4];
    float* optr[4];
    int qoff2[4];
#pragma unroll
    for (int qt = 0; qt < 4; ++qt) {
        const int q = qt * 16 + lr;
        const int qy = q >> 3, qx = q & 7;
        const size_t pix = ((size_t)(w * 128 + by * 8 + qy)) * 128 + bx * 8 + qx;
        optr[qt] = out + pix * 128 + head * 16 + cA * 4;
        qoff2[qt] = (qy + 13) * 21 + (qx + 13);
#pragma unroll
        for (int j = 0; j < 8; ++j) qf[qt][j] = 0;
        if (cA < 2)
            qf[qt] = *(const s16x8*)(qh + pix * 16 + cA * 8);
    }

    f32x4 accv[4];
    float sumf[4];
#pragma unroll
    for (int qt = 0; qt < 4; ++qt) {
        accv[qt] = (f32x4){0.f, 0.f, 0.f, 0.f};
        sumf[qt] = 0.f;
    }

    // prefetch pair 0 (lanes cA>=2 read V bytes; they multiply qf=0)
    s16x8 ak0 = *(const s16x8*)(kvh + keyoff[gbase]     + cA * 16);
    s16x8 ak1 = *(const s16x8*)(kvh + keyoff[gbase + 4] + cA * 16);

#pragma unroll 1
    for (int m = 0; m < 7; ++m) {
        // prefetch pair m+1 (keyoff padded to 256 -> always in-bounds)
        const int nx = 32 * (m + 1) + gbase;
        const s16x8 nk0 = *(const s16x8*)(kvh + keyoff[nx]     + cA * 16);
        const s16x8 nk1 = *(const s16x8*)(kvh + keyoff[nx + 4] + cA * 16);

        const int kb = 32 * m + cA * 8;                // this lane's 8 global keys
        const s16x8 kk = *(const s16x8*)&koff2[kb];
        const s16x8 vt = *(const s16x8*)&VT[w][lr][kb];   // PV A-frag (dim=lr)

#pragma unroll
        for (int qt = 0; qt < 4; ++qt) {
            const f32x4 sf0 = __builtin_amdgcn_mfma_f32_16x16x32_bf16(
                                  ak0, qf[qt], (f32x4){0.f, 0.f, 0.f, 0.f}, 0, 0, 0);
            const f32x4 sf1 = __builtin_amdgcn_mfma_f32_16x16x32_bf16(
                                  ak1, qf[qt], (f32x4){0.f, 0.f, 0.f, 0.f}, 0, 0, 0);
            float pr0[4], pr1[4];
#pragma unroll
            for (int r = 0; r < 4; ++r)
                pr0[r] = EXP2(fmaf(sf0[r], 0.36067376f, bias_l[qoff2[qt] - (int)kk[r]]));
#pragma unroll
            for (int r = 0; r < 4; ++r)
                pr1[r] = EXP2(fmaf(sf1[r], 0.36067376f, bias_l[qoff2[qt] - (int)kk[4 + r]]));
            sumf[qt] += ((pr0[0] + pr0[1]) + (pr0[2] + pr0[3]))
                      + ((pr1[0] + pr1[1]) + (pr1[2] + pr1[3]));

            const u32x4 pk = (u32x4){ cvtpk(pr0[0], pr0[1]), cvtpk(pr0[2], pr0[3]),
                                      cvtpk(pr1[0], pr1[1]), cvtpk(pr1[2], pr1[3]) };
            const s16x8 pb = *(const s16x8*)&pk;       // PV B-frag: keys 32m+cA*8+0..7
            accv[qt] = __builtin_amdgcn_mfma_f32_16x16x32_bf16(vt, pb, accv[qt], 0, 0, 0);
        }
        ak0 = nk0;
        ak1 = nk1;
    }

    // ---- reduce sums over cA groups (lanes lr, lr+16, lr+32, lr+48 share q)
#pragma unroll
    for (int qt = 0; qt < 4; ++qt) {
        float s = sumf[qt];
        s += __shfl_xor(s, 16);
        s += __shfl_xor(s, 32);
        const float inv = 1.0f / s;
        *(f32x4*)optr[qt] = accv[qt] * inv;
    }
}

// ---------------------------------------------------------------------------
extern "C" void kernel_launch(void* const* d_in, const int* in_sizes, int n_in,
                              void* d_out, int out_size, void* d_ws, size_t ws_size,
                              hipStream_t stream) {
    const float* x      = (const float*)d_in[0];
    const float* q_w    = (const float*)d_in[1];
    const float* kv_w   = (const float*)d_in[2];
    const float* pt     = (const float*)d_in[3];
    const float* proj_w = (const float*)d_in[4];
    const float* proj_b = (const float*)d_in[5];
    float* out = (float*)d_out;

    ushort* ykvb = (ushort*)d_ws;                                   // 32 MB head-major
    ushort* qb   = (ushort*)((char*)d_ws + 33554432);               // 16 MB head-major
    ushort* whi  = (ushort*)((char*)d_ws + 33554432 + 16777216);    // 128 KB
    ushort* wlo  = whi + 65536;                                     // 128 KB

    const dim3 blk(256);
    conv_w<<<dim3(256), blk, 0, stream>>>(q_w, kv_w, proj_w, whi, wlo);
    gemm_split<<<dim3(512), blk, 0, stream>>>(x, whi, wlo, 0, 3, 1,
                                              qb, ykvb, nullptr, nullptr);
    halo_attn<<<dim3(256, 8), blk, 0, stream>>>(out, qb, ykvb, pt);
    gemm_split<<<dim3(512), blk, 0, stream>>>(out, whi, wlo, 384, 1, 0,
                                              nullptr, nullptr, out, proj_b);
}

// Round 12
// 105.759 us; speedup vs baseline: 1.3129x; 1.1324x over previous
//
#include <hip/hip_runtime.h>
#include <float.h>

// HaloAttn: x(4,128,128,128) f32 -> out(4,128,128,128) f32
// BS=8, HS=3, WIN=14, NH=8, DQK=DV=16, SCALE=0.25
//
// k0: conv_w      q_w|kv_w|proj_w (512x128 f32) -> hi/lo bf16 in ws
// k1: gemm_split  q=x@q_w^T, kv=x@kv_w^T -> ws bf16 in HEAD-MAJOR layout
// k2: halo_attn   block=(spatial,head), wave=batch, 4 q-tiles/wave; all-builtin
//                 K=32 MFMA, permuted key order (QK C-frags concat == PV B-frag)
// k3: gemm_split  d_out = d_out @ proj_w^T + proj_b (in place, split MFMA)
//
// R12: gemm_split de-spilled — removed the __launch_bounds__(256,2) 128-VGPR
// clamp (R11 counters: VGPR=128 at cap, MfmaUtil 13%, VALU 8%, all-idle =
// scratch-stall signature) and restructured the kk loop to keep only one
// mf's x-frags live (live set ~115 regs).
//
// Head-major ws layout: kv[8][65536][32] ushort (k=d0..15, v=d16..31) @0 (32MB)
//   q[8][65536][16] ushort @32M (16MB) | whi[512][128] @48M | wlo (128KB each).
//
// Key permutation (pair m, sub-tile s, A-row i): global key g = 32m + (i>>2)*8 + 4s + (i&3).
// QK C-frag -> lane(lr,cA) holds S for keys 32m + cA*8 + 4s + r  (r=0..3).
// PV B-frag (16x16x32) needs keys 32m + cA*8 + j (j=0..7) -> concat s=0,s=1. No shuffles.

typedef float f32x4 __attribute__((ext_vector_type(4)));
typedef short s16x4 __attribute__((ext_vector_type(4)));
typedef short s16x8 __attribute__((ext_vector_type(8)));
typedef unsigned int u32x2 __attribute__((ext_vector_type(2)));
typedef unsigned int u32x4 __attribute__((ext_vector_type(4)));

__device__ inline ushort f2bf(float f) {   // RNE float->bf16 (cold paths)
    unsigned u = __float_as_uint(f);
    return (ushort)((u + 0x7FFF + ((u >> 16) & 1)) >> 16);
}
__device__ inline float bf2f(ushort h) { return __uint_as_float((unsigned)h << 16); }
__device__ inline unsigned cvtpk(float a, float b) {   // D[15:0]=bf16(a), D[31:16]=bf16(b)
    unsigned r;
    asm("v_cvt_pk_bf16_f32 %0, %1, %2" : "=v"(r) : "v"(a), "v"(b));
    return r;
}
#if __has_builtin(__builtin_amdgcn_exp2f)
#define EXP2(x) __builtin_amdgcn_exp2f(x)
#else
#define EXP2(x) exp2f(x)
#endif

// ---------------------------------------------------------------------------
// Weight split: rows 0-127 q_w, 128-383 kv_w, 384-511 proj_w. 65536 elems.
__global__ __launch_bounds__(256) void conv_w(
    const float* __restrict__ q_w, const float* __restrict__ kv_w,
    const float* __restrict__ proj_w, ushort* whi, ushort* wlo)
{
    const int g = blockIdx.x * 256 + threadIdx.x;      // 0..65535
    const int row = g >> 7, col = g & 127;
    const float v = (row < 128) ? q_w[row * 128 + col]
                  : (row < 384) ? kv_w[(row - 128) * 128 + col]
                                : proj_w[(row - 384) * 128 + col];
    const ushort h = f2bf(v);
    whi[g] = h;
    wlo[g] = f2bf(v - bf2f(h));
}

// ---------------------------------------------------------------------------
// Split-bf16 MFMA GEMM: C[row0..+127][chan] = A(fp32) @ W^T (+bias).
// Swapped operands: mfma(A=w_frag, B=x_frag) -> lane(l&15)=pixel holds 4
// consecutive chans. A-tile (full K=128) split hi/lo into swizzled LDS once
// per block; W-frags from global (L2-hot). 4 waves = 2x2 of 64x64.
// tok1 stores go to HEAD-MAJOR q/kv buffers.
__global__ __launch_bounds__(256) void gemm_split(
    const float* A,                                   // [M][128] fp32
    const ushort* __restrict__ Whi, const ushort* __restrict__ Wlo,
    int wbase, int ntc, int tok1,
    ushort* qb, ushort* kvb, float* outf, const float* __restrict__ bias)
{
    __shared__ ushort Ah[128 * 128];   // [row][k] swizzled 16B chunks, 32KB
    __shared__ ushort Al[128 * 128];

    const int t = threadIdx.x;
    const int row0 = blockIdx.x * 128;
    const int w = t >> 6, l = t & 63;
    const int wm = w >> 1, wn = w & 1;
    const int lr = l & 15, cA = l >> 4;

    // ---- stage + split A (coalesced float4; chunk-XOR swizzle: chunk^=(row&7))
#pragma unroll
    for (int i = 0; i < 16; ++i) {
        const int idx = t + i * 256;
        const int p = idx >> 5, fc = idx & 31;         // row, float4-col
        const float4 v = *(const float4*)(A + (size_t)(row0 + p) * 128 + fc * 4);
        const int base = p * 128 + (((fc >> 1) ^ (p & 7)) << 3) + (fc & 1) * 4;
        const unsigned h01 = cvtpk(v.x, v.y), h23 = cvtpk(v.z, v.w);
        *(u32x2*)&Ah[base] = (u32x2){h01, h23};
        const float hx = __uint_as_float(h01 << 16);
        const float hy = __uint_as_float(h01 & 0xFFFF0000u);
        const float hz = __uint_as_float(h23 << 16);
        const float hw = __uint_as_float(h23 & 0xFFFF0000u);
        *(u32x2*)&Al[base] = (u32x2){ cvtpk(v.x - hx, v.y - hy),
                                      cvtpk(v.z - hz, v.w - hw) };
    }
    __syncthreads();

#pragma unroll 1
    for (int nt = 0; nt < ntc; ++nt) {
        f32x4 acc[4][4];                               // [mf][nf]
#pragma unroll
        for (int mf = 0; mf < 4; ++mf)
#pragma unroll
            for (int nf = 0; nf < 4; ++nf) acc[mf][nf] = (f32x4){0.f,0.f,0.f,0.f};

#pragma unroll 1
        for (int kk = 0; kk < 4; ++kk) {
            // W-frags for this kk (32 VGPRs live)
            s16x8 wh[4], wl[4];
#pragma unroll
            for (int nf = 0; nf < 4; ++nf) {
                const size_t off = (size_t)(wbase + nt * 128 + wn * 64 + nf * 16 + lr) * 128
                                 + kk * 32 + cA * 8;
                wh[nf] = *(const s16x8*)&Whi[off];
                wl[nf] = *(const s16x8*)&Wlo[off];
            }
            // one mf at a time: only 8 VGPRs of x-frags live
#pragma unroll
            for (int mf = 0; mf < 4; ++mf) {
                const int p = wm * 64 + mf * 16 + lr;
                const int off = p * 128 + ((((kk << 2) + cA) ^ (p & 7)) << 3);
                const s16x8 xh = *(const s16x8*)&Ah[off];
                const s16x8 xl = *(const s16x8*)&Al[off];
#pragma unroll
                for (int nf = 0; nf < 4; ++nf) {
                    acc[mf][nf] = __builtin_amdgcn_mfma_f32_16x16x32_bf16(
                                      wh[nf], xh, acc[mf][nf], 0, 0, 0);
                    acc[mf][nf] = __builtin_amdgcn_mfma_f32_16x16x32_bf16(
                                      wh[nf], xl, acc[mf][nf], 0, 0, 0);
                    acc[mf][nf] = __builtin_amdgcn_mfma_f32_16x16x32_bf16(
                                      wl[nf], xh, acc[mf][nf], 0, 0, 0);
                }
            }
        }

        // ---- store: pixel = row0+wm*64+mf*16+lr, chan = wn*64+nf*16+cA*4+r
#pragma unroll
        for (int mf = 0; mf < 4; ++mf) {
            const size_t pix = row0 + wm * 64 + mf * 16 + lr;
#pragma unroll
            for (int nf = 0; nf < 4; ++nf) {
                const int chan = wn * 64 + nf * 16 + cA * 4;
                const f32x4 o = acc[mf][nf];
                if (tok1) {
                    const u32x2 pk = (u32x2){ cvtpk(o[0], o[1]), cvtpk(o[2], o[3]) };
                    if (nt == 0) {
                        // q head-major: q[head][pix][16], head = chan>>4, d = cA*4
                        const int head = wn * 4 + nf;
                        *(u32x2*)(qb + ((size_t)head << 20) + pix * 16 + (chan & 15)) = pk;
                    } else {
                        // kv head-major: kv[head][pix][32], k=d0..15 v=d16..31
                        const int gchan = (nt - 1) * 128 + chan;
                        const int head = gchan >> 5;
                        *(u32x2*)(kvb + ((size_t)head << 21) + pix * 32 + (gchan & 31)) = pk;
                    }
                } else {
                    const float4 bv = *(const float4*)(bias + chan);
                    f32x4 r = o;
                    r[0] += bv.x; r[1] += bv.y; r[2] += bv.z; r[3] += bv.w;
                    *(f32x4*)(outf + pix * 128 + chan) = r;
                }
            }
        }
    }
}

// ---------------------------------------------------------------------------
// MFMA halo attention. grid(256 spatial, 8 head), 256 thr = 4 waves = 4 BATCHES.
// Wave w = batch b: all 64 queries (4 q-tiles) of (b, head, spatial block).
// Per key-pair m: 2 ak gathers -> 8 QK MFMA (x4 q-tiles) + 4 PV MFMA.
// kv head-major: the wave's (head,batch) slice is 1MB -> L2-resident gathers.
__global__ __launch_bounds__(256) void halo_attn(
    float* out,                           // d_out fp32 (65536 x 128)
    const ushort* __restrict__ qg,        // ws q bf16 [8][65536][16] head-major
    const ushort* __restrict__ kvg,       // ws kv bf16 [8][65536][32] head-major
    const float* __restrict__ pos_table)  // (729, 8)
{
    __shared__ ushort VT[4][16][232];     // [batch][dim][key] bf16, stride 232   29696 B
    __shared__ float  bias_l[648];        // [0,441): bias*log2e; [441,648): sentinel
    __shared__ int    keyoff[256];        // byte offset into kv slice (0 if invalid/pad)
    __shared__ short  koff2[224];         // ky*21+kx, or -200 (sentinel) if invalid

    const int t  = threadIdx.x;
    const int bi = blockIdx.x, head = blockIdx.y;
    const int by = bi >> 4, bx = bi & 15;
    const int w  = t >> 6;                 // wave id = batch
    const int l  = t & 63;
    const int lr = l & 15;
    const int cA = l >> 4;

    // this wave's (head, batch) kv slice: 16384 pixels x 64B
    const char* kvh = (const char*)(kvg + ((size_t)head << 21) + ((size_t)w << 19));

    // ---- per-block LUTs (keys 196..223 pad; keyoff 224..255 prefetch pad)
    if (t < 224) {
        const int wy = t / 14, wx = t - (t / 14) * 14;
        const int py = by * 8 + wy - 3, px = bx * 8 + wx - 3;
        const bool valid = (t < 196) && ((unsigned)py < 128u) && ((unsigned)px < 128u);
        keyoff[t] = valid ? ((py * 128 + px) * 64) : 0;    // 64B per pixel record
        koff2[t]  = valid ? (short)(wy * 21 + wx) : (short)(-200);
    } else {
        keyoff[t] = 0;
    }
    for (int i = t; i < 648; i += 256) {
        if (i < 441) {
            const int ry = i / 21, rx = i - ry * 21;
            bias_l[i] = pos_table[((ry + 3) * 27 + rx + 3) * 8 + head] * 1.44269504f;
        } else {
            bias_l[i] = -30000.0f;         // sentinel: exp2 -> 0
        }
    }
    __syncthreads();

    // ---- stage V^T for this wave's batch (each lane: 2-key slots, 16 u32 writes)
    {
        const char* base = kvh + 32;       // v = d16..31 of each record
#pragma unroll 1
        for (int idx = l; idx < 112; idx += 64) {
            const char* s0 = base + keyoff[2 * idx];
            const char* s1 = base + keyoff[2 * idx + 1];
            const s16x8 a0 = *(const s16x8*)s0;
            const s16x8 a1 = *(const s16x8*)(s0 + 16);
            const s16x8 c0 = *(const s16x8*)s1;
            const s16x8 c1 = *(const s16x8*)(s1 + 16);
#pragma unroll
            for (int j = 0; j < 8; ++j) {
                *(unsigned*)&VT[w][j][2 * idx] =
                    ((unsigned)(ushort)c0[j] << 16) | (ushort)a0[j];
                *(unsigned*)&VT[w][j + 8][2 * idx] =
                    ((unsigned)(ushort)c1[j] << 16) | (ushort)a1[j];
            }
        }
    }
    __syncthreads();

    // ---- per-wave setup: 4 q-tiles (q = qt*16 + lr), batch = w
    const int gbase = ((lr >> 2) << 3) + (lr & 3);   // key-permutation base for A-row lr
    const ushort* qh = qg + ((size_t)head << 20);
    s16x8 qf[4];
    float* optr[4];
    int qoff2[4];
#pragma unroll
    for (int qt = 0; qt < 4; ++qt) {
        const int q = qt * 16 + lr;
        const int qy = q >> 3, qx = q & 7;
        const size_t pix = ((size_t)(w * 128 + by * 8 + qy)) * 128 + bx * 8 + qx;
        optr[qt] = out + pix * 128 + head * 16 + cA * 4;
        qoff2[qt] = (qy + 13) * 21 + (qx + 13);
#pragma unroll
        for (int j = 0; j < 8; ++j) qf[qt][j] = 0;
        if (cA < 2)
            qf[qt] = *(const s16x8*)(qh + pix * 16 + cA * 8);
    }

    f32x4 accv[4];
    float sumf[4];
#pragma unroll
    for (int qt = 0; qt < 4; ++qt) {
        accv[qt] = (f32x4){0.f, 0.f, 0.f, 0.f};
        sumf[qt] = 0.f;
    }

    // prefetch pair 0 (lanes cA>=2 read V bytes; they multiply qf=0)
    s16x8 ak0 = *(const s16x8*)(kvh + keyoff[gbase]     + cA * 16);
    s16x8 ak1 = *(const s16x8*)(kvh + keyoff[gbase + 4] + cA * 16);

#pragma unroll 1
    for (int m = 0; m < 7; ++m) {
        // prefetch pair m+1 (keyoff padded to 256 -> always in-bounds)
        const int nx = 32 * (m + 1) + gbase;
        const s16x8 nk0 = *(const s16x8*)(kvh + keyoff[nx]     + cA * 16);
        const s16x8 nk1 = *(const s16x8*)(kvh + keyoff[nx + 4] + cA * 16);

        const int kb = 32 * m + cA * 8;                // this lane's 8 global keys
        const s16x8 kk = *(const s16x8*)&koff2[kb];
        const s16x8 vt = *(const s16x8*)&VT[w][lr][kb];   // PV A-frag (dim=lr)

#pragma unroll
        for (int qt = 0; qt < 4; ++qt) {
            const f32x4 sf0 = __builtin_amdgcn_mfma_f32_16x16x32_bf16(
                                  ak0, qf[qt], (f32x4){0.f, 0.f, 0.f, 0.f}, 0, 0, 0);
            const f32x4 sf1 = __builtin_amdgcn_mfma_f32_16x16x32_bf16(
                                  ak1, qf[qt], (f32x4){0.f, 0.f, 0.f, 0.f}, 0, 0, 0);
            float pr0[4], pr1[4];
#pragma unroll
            for (int r = 0; r < 4; ++r)
                pr0[r] = EXP2(fmaf(sf0[r], 0.36067376f, bias_l[qoff2[qt] - (int)kk[r]]));
#pragma unroll
            for (int r = 0; r < 4; ++r)
                pr1[r] = EXP2(fmaf(sf1[r], 0.36067376f, bias_l[qoff2[qt] - (int)kk[4 + r]]));
            sumf[qt] += ((pr0[0] + pr0[1]) + (pr0[2] + pr0[3]))
                      + ((pr1[0] + pr1[1]) + (pr1[2] + pr1[3]));

            const u32x4 pk = (u32x4){ cvtpk(pr0[0], pr0[1]), cvtpk(pr0[2], pr0[3]),
                                      cvtpk(pr1[0], pr1[1]), cvtpk(pr1[2], pr1[3]) };
            const s16x8 pb = *(const s16x8*)&pk;       // PV B-frag: keys 32m+cA*8+0..7
            accv[qt] = __builtin_amdgcn_mfma_f32_16x16x32_bf16(vt, pb, accv[qt], 0, 0, 0);
        }
        ak0 = nk0;
        ak1 = nk1;
    }

    // ---- reduce sums over cA groups (lanes lr, lr+16, lr+32, lr+48 share q)
#pragma unroll
    for (int qt = 0; qt < 4; ++qt) {
        float s = sumf[qt];
        s += __shfl_xor(s, 16);
        s += __shfl_xor(s, 32);
        const float inv = 1.0f / s;
        *(f32x4*)optr[qt] = accv[qt] * inv;
    }
}

// ---------------------------------------------------------------------------
extern "C" void kernel_launch(void* const* d_in, const int* in_sizes, int n_in,
                              void* d_out, int out_size, void* d_ws, size_t ws_size,
                              hipStream_t stream) {
    const float* x      = (const float*)d_in[0];
    const float* q_w    = (const float*)d_in[1];
    const float* kv_w   = (const float*)d_in[2];
    const float* pt     = (const float*)d_in[3];
    const float* proj_w = (const float*)d_in[4];
    const float* proj_b = (const float*)d_in[5];
    float* out = (float*)d_out;

    ushort* ykvb = (ushort*)d_ws;                                   // 32 MB head-major
    ushort* qb   = (ushort*)((char*)d_ws + 33554432);               // 16 MB head-major
    ushort* whi  = (ushort*)((char*)d_ws + 33554432 + 16777216);    // 128 KB
    ushort* wlo  = whi + 65536;                                     // 128 KB

    const dim3 blk(256);
    conv_w<<<dim3(256), blk, 0, stream>>>(q_w, kv_w, proj_w, whi, wlo);
    gemm_split<<<dim3(512), blk, 0, stream>>>(x, whi, wlo, 0, 3, 1,
                                              qb, ykvb, nullptr, nullptr);
    halo_attn<<<dim3(256, 8), blk, 0, stream>>>(out, qb, ykvb, pt);
    gemm_split<<<dim3(512), blk, 0, stream>>>(out, whi, wlo, 384, 1, 0,
                                              nullptr, nullptr, out, proj_b);
}

// Round 13
// 94.134 us; speedup vs baseline: 1.4750x; 1.1235x over previous
//
#include <hip/hip_runtime.h>
#include <float.h>

// HaloAttn: x(4,128,128,128) f32 -> out(4,128,128,128) f32
// BS=8, HS=3, WIN=14, NH=8, DQK=DV=16, SCALE=0.25
//
// k0: conv_w      weights -> hi/lo bf16 in FRAG-MAJOR layout W'[rb][kc][lr][8]
// k1: gemm_split  q=x@q_w^T, kv=x@kv_w^T -> ws bf16 head-major (split MFMA)
// k2: halo_attn   block=(spatial,head,batch-pair), wave=(batch,q-half);
//                 all-builtin K=32 MFMA, permuted key order
// k3: gemm_split  d_out = d_out @ proj_w^T + proj_b (in place)
//
// R13: (a) halo 2-batch blocks: VT[2] -> LDS 18.9KB -> 8 blocks/CU (100% wave cap);
//      (b) frag-major weights: every wh/wl wave-load is 1KB contiguous.
//
// Head-major ws: kv[8][65536][32] ushort @0 (32MB) | q[8][65536][16] @32M (16MB)
//   | whi' @48M | wlo' (128KB each, frag-major).
//
// Key permutation (pair m, sub-tile s, A-row i): g = 32m + (i>>2)*8 + 4s + (i&3).
// QK C-frag: lane(lr,cA) holds S for keys 32m + cA*8 + 4s + r.
// PV B-frag needs keys 32m + cA*8 + j -> concat s=0,s=1 frags. No shuffles.

typedef float f32x4 __attribute__((ext_vector_type(4)));
typedef short s16x4 __attribute__((ext_vector_type(4)));
typedef short s16x8 __attribute__((ext_vector_type(8)));
typedef unsigned int u32x2 __attribute__((ext_vector_type(2)));
typedef unsigned int u32x4 __attribute__((ext_vector_type(4)));

__device__ inline ushort f2bf(float f) {   // RNE float->bf16 (cold paths)
    unsigned u = __float_as_uint(f);
    return (ushort)((u + 0x7FFF + ((u >> 16) & 1)) >> 16);
}
__device__ inline float bf2f(ushort h) { return __uint_as_float((unsigned)h << 16); }
__device__ inline unsigned cvtpk(float a, float b) {   // D[15:0]=bf16(a), D[31:16]=bf16(b)
    unsigned r;
    asm("v_cvt_pk_bf16_f32 %0, %1, %2" : "=v"(r) : "v"(a), "v"(b));
    return r;
}
#if __has_builtin(__builtin_amdgcn_exp2f)
#define EXP2(x) __builtin_amdgcn_exp2f(x)
#else
#define EXP2(x) exp2f(x)
#endif

// ---------------------------------------------------------------------------
// Weight split into FRAG-MAJOR layout: rows 0-127 q_w, 128-383 kv_w, 384-511
// proj_w. W'[(row>>4)][col>>3][row&15][col&7]: a wave-load of 64 lanes
// (cA=lane>>4, lr=lane&15) reading rb,kk is 1024 contiguous bytes.
__global__ __launch_bounds__(256) void conv_w(
    const float* __restrict__ q_w, const float* __restrict__ kv_w,
    const float* __restrict__ proj_w, ushort* whi, ushort* wlo)
{
    const int g = blockIdx.x * 256 + threadIdx.x;      // 0..65535
    const int row = g >> 7, col = g & 127;
    const float v = (row < 128) ? q_w[row * 128 + col]
                  : (row < 384) ? kv_w[(row - 128) * 128 + col]
                                : proj_w[(row - 384) * 128 + col];
    const ushort h = f2bf(v);
    const int off = ((row >> 4) * 2048) + ((col >> 3) * 128) + ((row & 15) * 8) + (col & 7);
    whi[off] = h;
    wlo[off] = f2bf(v - bf2f(h));
}

// ---------------------------------------------------------------------------
// Split-bf16 MFMA GEMM: C[row0..+127][chan] = A(fp32) @ W^T (+bias).
// Swapped operands: mfma(A=w_frag, B=x_frag) -> lane(l&15)=pixel holds 4
// consecutive chans. A-tile (full K=128) split hi/lo into swizzled LDS once
// per block; W-frags from global, frag-major (coalesced 1KB wave-loads).
__global__ __launch_bounds__(256) void gemm_split(
    const float* A,                                   // [M][128] fp32
    const ushort* __restrict__ Whi, const ushort* __restrict__ Wlo,
    int wbase, int ntc, int tok1,
    ushort* qb, ushort* kvb, float* outf, const float* __restrict__ bias)
{
    __shared__ ushort Ah[128 * 128];   // [row][k] swizzled 16B chunks, 32KB
    __shared__ ushort Al[128 * 128];

    const int t = threadIdx.x;
    const int row0 = blockIdx.x * 128;
    const int w = t >> 6, l = t & 63;
    const int wm = w >> 1, wn = w & 1;
    const int lr = l & 15, cA = l >> 4;

    // ---- stage + split A (coalesced float4; chunk-XOR swizzle: chunk^=(row&7))
#pragma unroll
    for (int i = 0; i < 16; ++i) {
        const int idx = t + i * 256;
        const int p = idx >> 5, fc = idx & 31;         // row, float4-col
        const float4 v = *(const float4*)(A + (size_t)(row0 + p) * 128 + fc * 4);
        const int base = p * 128 + (((fc >> 1) ^ (p & 7)) << 3) + (fc & 1) * 4;
        const unsigned h01 = cvtpk(v.x, v.y), h23 = cvtpk(v.z, v.w);
        *(u32x2*)&Ah[base] = (u32x2){h01, h23};
        const float hx = __uint_as_float(h01 << 16);
        const float hy = __uint_as_float(h01 & 0xFFFF0000u);
        const float hz = __uint_as_float(h23 << 16);
        const float hw = __uint_as_float(h23 & 0xFFFF0000u);
        *(u32x2*)&Al[base] = (u32x2){ cvtpk(v.x - hx, v.y - hy),
                                      cvtpk(v.z - hz, v.w - hw) };
    }
    __syncthreads();

#pragma unroll 1
    for (int nt = 0; nt < ntc; ++nt) {
        f32x4 acc[4][4];                               // [mf][nf]
#pragma unroll
        for (int mf = 0; mf < 4; ++mf)
#pragma unroll
            for (int nf = 0; nf < 4; ++nf) acc[mf][nf] = (f32x4){0.f,0.f,0.f,0.f};

#pragma unroll 1
        for (int kk = 0; kk < 4; ++kk) {
            // W-frags for this kk (frag-major: 1KB contiguous per wave-load)
            s16x8 wh[4], wl[4];
#pragma unroll
            for (int nf = 0; nf < 4; ++nf) {
                const int rb = (wbase >> 4) + nt * 8 + wn * 4 + nf;
                const size_t off = (size_t)rb * 2048 + (kk * 4 + cA) * 128 + lr * 8;
                wh[nf] = *(const s16x8*)&Whi[off];
                wl[nf] = *(const s16x8*)&Wlo[off];
            }
            // one mf at a time: only 8 VGPRs of x-frags live
#pragma unroll
            for (int mf = 0; mf < 4; ++mf) {
                const int p = wm * 64 + mf * 16 + lr;
                const int off = p * 128 + ((((kk << 2) + cA) ^ (p & 7)) << 3);
                const s16x8 xh = *(const s16x8*)&Ah[off];
                const s16x8 xl = *(const s16x8*)&Al[off];
#pragma unroll
                for (int nf = 0; nf < 4; ++nf) {
                    acc[mf][nf] = __builtin_amdgcn_mfma_f32_16x16x32_bf16(
                                      wh[nf], xh, acc[mf][nf], 0, 0, 0);
                    acc[mf][nf] = __builtin_amdgcn_mfma_f32_16x16x32_bf16(
                                      wh[nf], xl, acc[mf][nf], 0, 0, 0);
                    acc[mf][nf] = __builtin_amdgcn_mfma_f32_16x16x32_bf16(
                                      wl[nf], xh, acc[mf][nf], 0, 0, 0);
                }
            }
        }

        // ---- store: pixel = row0+wm*64+mf*16+lr, chan = wn*64+nf*16+cA*4+r
#pragma unroll
        for (int mf = 0; mf < 4; ++mf) {
            const size_t pix = row0 + wm * 64 + mf * 16 + lr;
#pragma unroll
            for (int nf = 0; nf < 4; ++nf) {
                const int chan = wn * 64 + nf * 16 + cA * 4;
                const f32x4 o = acc[mf][nf];
                if (tok1) {
                    const u32x2 pk = (u32x2){ cvtpk(o[0], o[1]), cvtpk(o[2], o[3]) };
                    if (nt == 0) {
                        // q head-major: q[head][pix][16]
                        const int head = wn * 4 + nf;
                        *(u32x2*)(qb + ((size_t)head << 20) + pix * 16 + (chan & 15)) = pk;
                    } else {
                        // kv head-major: kv[head][pix][32], k=d0..15 v=d16..31
                        const int gchan = (nt - 1) * 128 + chan;
                        const int head = gchan >> 5;
                        *(u32x2*)(kvb + ((size_t)head << 21) + pix * 32 + (gchan & 31)) = pk;
                    }
                } else {
                    const float4 bv = *(const float4*)(bias + chan);
                    f32x4 r = o;
                    r[0] += bv.x; r[1] += bv.y; r[2] += bv.z; r[3] += bv.w;
                    *(f32x4*)(outf + pix * 128 + chan) = r;
                }
            }
        }
    }
}

// ---------------------------------------------------------------------------
// MFMA halo attention. grid(256 spatial, 8 head, 2 batch-pair), 256 thr =
// 4 waves = 2 batches x 2 q-halves. Wave w: batch = bp*2+(w>>1), q-tiles
// {(w&1)*2, (w&1)*2+1}. LDS 18.9KB -> 8 blocks/CU (100% wave cap).
// kv head-major: (head,batch) slice = 1MB, L2-resident gathers.
__global__ __launch_bounds__(256) void halo_attn(
    float* out,                           // d_out fp32 (65536 x 128)
    const ushort* __restrict__ qg,        // ws q bf16 [8][65536][16] head-major
    const ushort* __restrict__ kvg,       // ws kv bf16 [8][65536][32] head-major
    const float* __restrict__ pos_table)  // (729, 8)
{
    __shared__ ushort VT[2][16][232];     // [local batch][dim][key]  14848 B
    __shared__ float  bias_l[648];        // [0,441): bias*log2e; rest sentinel
    __shared__ int    keyoff[256];        // byte offset into kv slice
    __shared__ short  koff2[224];         // ky*21+kx, or -200 if invalid

    const int t  = threadIdx.x;
    const int bi = blockIdx.x, head = blockIdx.y, bp = blockIdx.z;
    const int by = bi >> 4, bx = bi & 15;
    const int w  = t >> 6;
    const int lb = w >> 1;                 // local batch 0/1
    const int qh = w & 1;                  // q-half
    const int batch = bp * 2 + lb;
    const int l  = t & 63;
    const int lr = l & 15;
    const int cA = l >> 4;

    // this wave's (head, batch) kv slice: 16384 pixels x 64B
    const char* kvh = (const char*)(kvg + ((size_t)head << 21) + ((size_t)batch << 19));

    // ---- per-block LUTs (keys 196..223 pad; keyoff 224..255 prefetch pad)
    if (t < 224) {
        const int wy = t / 14, wx = t - (t / 14) * 14;
        const int py = by * 8 + wy - 3, px = bx * 8 + wx - 3;
        const bool valid = (t < 196) && ((unsigned)py < 128u) && ((unsigned)px < 128u);
        keyoff[t] = valid ? ((py * 128 + px) * 64) : 0;    // 64B per pixel record
        koff2[t]  = valid ? (short)(wy * 21 + wx) : (short)(-200);
    } else {
        keyoff[t] = 0;
    }
    for (int i = t; i < 648; i += 256) {
        if (i < 441) {
            const int ry = i / 21, rx = i - ry * 21;
            bias_l[i] = pos_table[((ry + 3) * 27 + rx + 3) * 8 + head] * 1.44269504f;
        } else {
            bias_l[i] = -30000.0f;         // sentinel: exp2 -> 0
        }
    }
    __syncthreads();

    // ---- stage V^T: 2 waves per batch, combined lane id l2 = qh*64+l < 112
    {
        const int l2 = qh * 64 + l;
        if (l2 < 112) {
            const char* base = kvh + 32;   // v = d16..31 of each record
            const char* s0 = base + keyoff[2 * l2];
            const char* s1 = base + keyoff[2 * l2 + 1];
            const s16x8 a0 = *(const s16x8*)s0;
            const s16x8 a1 = *(const s16x8*)(s0 + 16);
            const s16x8 c0 = *(const s16x8*)s1;
            const s16x8 c1 = *(const s16x8*)(s1 + 16);
#pragma unroll
            for (int j = 0; j < 8; ++j) {
                *(unsigned*)&VT[lb][j][2 * l2] =
                    ((unsigned)(ushort)c0[j] << 16) | (ushort)a0[j];
                *(unsigned*)&VT[lb][j + 8][2 * l2] =
                    ((unsigned)(ushort)c1[j] << 16) | (ushort)a1[j];
            }
        }
    }
    __syncthreads();

    // ---- per-wave setup: 2 q-tiles (qt = qh*2 + j)
    const int gbase = ((lr >> 2) << 3) + (lr & 3);   // key-permutation base
    const ushort* qhp = qg + ((size_t)head << 20);
    s16x8 qf[2];
    float* optr[2];
    int qoff2[2];
#pragma unroll
    for (int j = 0; j < 2; ++j) {
        const int q = (qh * 2 + j) * 16 + lr;
        const int qy = q >> 3, qx = q & 7;
        const size_t pix = ((size_t)(batch * 128 + by * 8 + qy)) * 128 + bx * 8 + qx;
        optr[j] = out + pix * 128 + head * 16 + cA * 4;
        qoff2[j] = (qy + 13) * 21 + (qx + 13);
#pragma unroll
        for (int k = 0; k < 8; ++k) qf[j][k] = 0;
        if (cA < 2)
            qf[j] = *(const s16x8*)(qhp + pix * 16 + cA * 8);
    }

    f32x4 accv[2];
    float sumf[2];
#pragma unroll
    for (int j = 0; j < 2; ++j) {
        accv[j] = (f32x4){0.f, 0.f, 0.f, 0.f};
        sumf[j] = 0.f;
    }

    // prefetch pair 0 (lanes cA>=2 read V bytes; they multiply qf=0)
    s16x8 ak0 = *(const s16x8*)(kvh + keyoff[gbase]     + cA * 16);
    s16x8 ak1 = *(const s16x8*)(kvh + keyoff[gbase + 4] + cA * 16);

#pragma unroll 1
    for (int m = 0; m < 7; ++m) {
        // prefetch pair m+1 (keyoff padded to 256 -> always in-bounds)
        const int nx = 32 * (m + 1) + gbase;
        const s16x8 nk0 = *(const s16x8*)(kvh + keyoff[nx]     + cA * 16);
        const s16x8 nk1 = *(const s16x8*)(kvh + keyoff[nx + 4] + cA * 16);

        const int kb = 32 * m + cA * 8;                // this lane's 8 global keys
        const s16x8 kk = *(const s16x8*)&koff2[kb];
        const s16x8 vt = *(const s16x8*)&VT[lb][lr][kb];  // PV A-frag (dim=lr)

#pragma unroll
        for (int j = 0; j < 2; ++j) {
            const f32x4 sf0 = __builtin_amdgcn_mfma_f32_16x16x32_bf16(
                                  ak0, qf[j], (f32x4){0.f, 0.f, 0.f, 0.f}, 0, 0, 0);
            const f32x4 sf1 = __builtin_amdgcn_mfma_f32_16x16x32_bf16(
                                  ak1, qf[j], (f32x4){0.f, 0.f, 0.f, 0.f}, 0, 0, 0);
            float pr0[4], pr1[4];
#pragma unroll
            for (int r = 0; r < 4; ++r)
                pr0[r] = EXP2(fmaf(sf0[r], 0.36067376f, bias_l[qoff2[j] - (int)kk[r]]));
#pragma unroll
            for (int r = 0; r < 4; ++r)
                pr1[r] = EXP2(fmaf(sf1[r], 0.36067376f, bias_l[qoff2[j] - (int)kk[4 + r]]));
            sumf[j] += ((pr0[0] + pr0[1]) + (pr0[2] + pr0[3]))
                     + ((pr1[0] + pr1[1]) + (pr1[2] + pr1[3]));

            const u32x4 pk = (u32x4){ cvtpk(pr0[0], pr0[1]), cvtpk(pr0[2], pr0[3]),
                                      cvtpk(pr1[0], pr1[1]), cvtpk(pr1[2], pr1[3]) };
            const s16x8 pb = *(const s16x8*)&pk;       // PV B-frag: keys 32m+cA*8+0..7
            accv[j] = __builtin_amdgcn_mfma_f32_16x16x32_bf16(vt, pb, accv[j], 0, 0, 0);
        }
        ak0 = nk0;
        ak1 = nk1;
    }

    // ---- reduce sums over cA groups (lanes lr, lr+16, lr+32, lr+48 share q)
#pragma unroll
    for (int j = 0; j < 2; ++j) {
        float s = sumf[j];
        s += __shfl_xor(s, 16);
        s += __shfl_xor(s, 32);
        const float inv = 1.0f / s;
        *(f32x4*)optr[j] = accv[j] * inv;
    }
}

// ---------------------------------------------------------------------------
extern "C" void kernel_launch(void* const* d_in, const int* in_sizes, int n_in,
                              void* d_out, int out_size, void* d_ws, size_t ws_size,
                              hipStream_t stream) {
    const float* x      = (const float*)d_in[0];
    const float* q_w    = (const float*)d_in[1];
    const float* kv_w   = (const float*)d_in[2];
    const float* pt     = (const float*)d_in[3];
    const float* proj_w = (const float*)d_in[4];
    const float* proj_b = (const float*)d_in[5];
    float* out = (float*)d_out;

    ushort* ykvb = (ushort*)d_ws;                                   // 32 MB head-major
    ushort* qb   = (ushort*)((char*)d_ws + 33554432);               // 16 MB head-major
    ushort* whi  = (ushort*)((char*)d_ws + 33554432 + 16777216);    // 128 KB frag-major
    ushort* wlo  = whi + 65536;                                     // 128 KB

    const dim3 blk(256);
    conv_w<<<dim3(256), blk, 0, stream>>>(q_w, kv_w, proj_w, whi, wlo);
    gemm_split<<<dim3(512), blk, 0, stream>>>(x, whi, wlo, 0, 3, 1,
                                              qb, ykvb, nullptr, nullptr);
    halo_attn<<<dim3(256, 8, 2), blk, 0, stream>>>(out, qb, ykvb, pt);
    gemm_split<<<dim3(512), blk, 0, stream>>>(out, whi, wlo, 384, 1, 0,
                                              nullptr, nullptr, out, proj_b);
}